// Round 1
// baseline (795.843 us; speedup 1.0000x reference)
//
#include <hip/hip_runtime.h>

#define N_NODES 100000
#define N_EDGES 1600000
#define HDIM 128
#define NUM_CARDS 110

// ---------------- CSR build ----------------

__global__ void k_count(const int* __restrict__ dst, int* __restrict__ deg) {
    int e = blockIdx.x * blockDim.x + threadIdx.x;
    if (e < N_EDGES) atomicAdd(&deg[dst[e]], 1);
}

// blocks of 1024 elements (256 threads x 4), exclusive scan within block
__global__ void k_scan1(const int* __restrict__ deg, int* __restrict__ part,
                        int* __restrict__ bsum) {
    __shared__ int sdata[256];
    int b = blockIdx.x, t = threadIdx.x;
    int base = b * 1024 + t * 4;
    int v[4];
#pragma unroll
    for (int i = 0; i < 4; i++) {
        int n = base + i;
        v[i] = (n < N_NODES) ? deg[n] : 0;
    }
    int s0 = v[0] + v[1] + v[2] + v[3];
    sdata[t] = s0;
    __syncthreads();
    for (int off = 1; off < 256; off <<= 1) {
        int x = (t >= off) ? sdata[t - off] : 0;
        __syncthreads();
        sdata[t] += x;
        __syncthreads();
    }
    int run = sdata[t] - s0;  // exclusive prefix of this thread's 4
#pragma unroll
    for (int i = 0; i < 4; i++) {
        int n = base + i;
        if (n < N_NODES) part[n] = run;
        run += v[i];
    }
    if (t == 255) bsum[b] = sdata[255];
}

__global__ void k_scan2(int* __restrict__ bsum, int nb) {
    __shared__ int s[128];
    int t = threadIdx.x;
    int v = (t < nb) ? bsum[t] : 0;
    s[t] = v;
    __syncthreads();
    for (int off = 1; off < 128; off <<= 1) {
        int x = (t >= off) ? s[t - off] : 0;
        __syncthreads();
        s[t] += x;
        __syncthreads();
    }
    if (t < nb) bsum[t] = s[t] - v;  // exclusive
}

__global__ void k_scan3(int* __restrict__ row_off, const int* __restrict__ bsum,
                        const int* __restrict__ deg, float* __restrict__ deg_inv) {
    int n = blockIdx.x * blockDim.x + threadIdx.x;
    if (n < N_NODES) {
        row_off[n] += bsum[n >> 10];
        int d = deg[n];
        deg_inv[n] = (d > 0) ? 1.0f / (float)d : 0.0f;
    }
}

__global__ void k_fill(const int* __restrict__ src, const int* __restrict__ dst,
                       const int* __restrict__ row_off, int* __restrict__ cursor,
                       int* __restrict__ csr_src) {
    int e = blockIdx.x * blockDim.x + threadIdx.x;
    if (e < N_EDGES) {
        int d = dst[e];
        int p = row_off[d] + atomicAdd(&cursor[d], 1);
        csr_src[p] = src[e];
    }
}

// ---------------- fused dual GEMM: G = A@WL^T, R = A@WR^T + bL + bR ----------------
// A: [N,128] f32 row-major. WL/WR: [128, ld] row-major (ld=129 w/ cards col, or 128).
// 32 rows/block, K chunked by 32, thread micro-tile 4 rows x 4 cols x 2 outputs.

#define BM 32
#define BK 32

__global__ __launch_bounds__(256, 4) void k_gemm_dual(
    const float* __restrict__ A, const int* __restrict__ cards,
    const float* __restrict__ WL, const float* __restrict__ WR,
    const float* __restrict__ bL, const float* __restrict__ bR,
    float* __restrict__ G, float* __restrict__ R, int ld, int has_card) {
    __shared__ float sA[BM][BK + 1];
    __shared__ float sBL[BK][HDIM];
    __shared__ float sBR[BK][HDIM];
    const int t = threadIdx.x;
    const int row0 = blockIdx.x * BM;
    const int tx = t & 31;  // j-group: cols tx*4 .. tx*4+3
    const int ty = t >> 5;  // row-group: rows ty*4 .. ty*4+3

    float accG[4][4] = {{0}};
    float accR[4][4] = {{0}};

    for (int k0 = 0; k0 < HDIM; k0 += BK) {
        {   // stage A chunk: 32 rows x 32 k
            int r = t >> 3;
            int kk = (t & 7) * 4;
            const float4 av = *(const float4*)&A[(size_t)(row0 + r) * HDIM + k0 + kk];
            sA[r][kk + 0] = av.x; sA[r][kk + 1] = av.y;
            sA[r][kk + 2] = av.z; sA[r][kk + 3] = av.w;
        }
        {   // stage weight chunks transposed: sB[k][j] = W[j*ld + k0 + k]
            int j = t >> 1;
            int kb = (t & 1) * 16;
            const float* wl = &WL[(size_t)j * ld + k0 + kb];
            const float* wr = &WR[(size_t)j * ld + k0 + kb];
#pragma unroll
            for (int u = 0; u < 16; u++) {
                sBL[kb + u][j] = wl[u];
                sBR[kb + u][j] = wr[u];
            }
        }
        __syncthreads();
#pragma unroll
        for (int k = 0; k < BK; k++) {
            float a[4];
#pragma unroll
            for (int i = 0; i < 4; i++) a[i] = sA[ty * 4 + i][k];
            const float4 blv = *(const float4*)&sBL[k][tx * 4];
            const float4 brv = *(const float4*)&sBR[k][tx * 4];
            const float bl[4] = {blv.x, blv.y, blv.z, blv.w};
            const float br[4] = {brv.x, brv.y, brv.z, brv.w};
#pragma unroll
            for (int i = 0; i < 4; i++)
#pragma unroll
                for (int jj = 0; jj < 4; jj++) {
                    accG[i][jj] += a[i] * bl[jj];
                    accR[i][jj] += a[i] * br[jj];
                }
        }
        __syncthreads();
    }

#pragma unroll
    for (int i = 0; i < 4; i++) {
        const int n = row0 + ty * 4 + i;
        float cv = has_card ? (float)cards[n] : 0.0f;
        float4 go, ro;
        float* gp = (float*)&go;
        float* rp = (float*)&ro;
#pragma unroll
        for (int jj = 0; jj < 4; jj++) {
            const int j = tx * 4 + jj;
            float g = accG[i][jj];
            float r = accR[i][jj] + bL[j] + bR[j];
            if (has_card) {
                g += cv * WL[(size_t)j * ld + HDIM];
                r += cv * WR[(size_t)j * ld + HDIM];
            }
            gp[jj] = g;
            rp[jj] = r;
        }
        *(float4*)&G[(size_t)n * HDIM + tx * 4] = go;
        *(float4*)&R[(size_t)n * HDIM + tx * 4] = ro;
    }
}

// ---------------- aggregate: out = relu(sum(G[src]) * deg_inv + R) ----------------
// one wave (64 lanes) per node; lane handles float2 at feature 2*lane.

__global__ __launch_bounds__(256) void k_agg(
    const float* __restrict__ G, const float* __restrict__ Rm,
    const int* __restrict__ row_off, const int* __restrict__ deg,
    const float* __restrict__ deg_inv, const int* __restrict__ csr_src,
    float* __restrict__ out) {
    const int wave = threadIdx.x >> 6;
    const int lane = threadIdx.x & 63;
    const int n = blockIdx.x * 4 + wave;
    if (n >= N_NODES) return;
    const int start = row_off[n];
    const int d = deg[n];
    const int f = lane * 2;
    float2 s0 = {0.f, 0.f}, s1 = {0.f, 0.f};
    int j = 0;
    for (; j + 1 < d; j += 2) {
        const int u0 = csr_src[start + j];
        const int u1 = csr_src[start + j + 1];
        const float2 g0 = *(const float2*)&G[(size_t)u0 * HDIM + f];
        const float2 g1 = *(const float2*)&G[(size_t)u1 * HDIM + f];
        s0.x += g0.x; s0.y += g0.y;
        s1.x += g1.x; s1.y += g1.y;
    }
    if (j < d) {
        const int u0 = csr_src[start + j];
        const float2 g0 = *(const float2*)&G[(size_t)u0 * HDIM + f];
        s0.x += g0.x; s0.y += g0.y;
    }
    const float di = deg_inv[n];
    const float2 r = *(const float2*)&Rm[(size_t)n * HDIM + f];
    float2 o;
    o.x = fmaxf((s0.x + s1.x) * di + r.x, 0.0f);
    o.y = fmaxf((s0.y + s1.y) * di + r.y, 0.0f);
    *(float2*)&out[(size_t)n * HDIM + f] = o;
}

// ---------------- output GEMM: logits = H @ Wo^T + bo, J = 110 ----------------

__global__ __launch_bounds__(256, 4) void k_gemm_out(
    const float* __restrict__ A, const float* __restrict__ W,
    const float* __restrict__ bias, float* __restrict__ out) {
    __shared__ float sA[BM][BK + 1];
    __shared__ float sB[BK][HDIM];
    const int t = threadIdx.x;
    const int row0 = blockIdx.x * BM;
    const int tx = t & 31;
    const int ty = t >> 5;

    float acc[4][4] = {{0}};

    for (int k0 = 0; k0 < HDIM; k0 += BK) {
        {
            int r = t >> 3;
            int kk = (t & 7) * 4;
            const float4 av = *(const float4*)&A[(size_t)(row0 + r) * HDIM + k0 + kk];
            sA[r][kk + 0] = av.x; sA[r][kk + 1] = av.y;
            sA[r][kk + 2] = av.z; sA[r][kk + 3] = av.w;
        }
        {
            int j = t >> 1;
            int kb = (t & 1) * 16;
            if (j < NUM_CARDS) {
                const float* wp = &W[(size_t)j * HDIM + k0 + kb];
#pragma unroll
                for (int u = 0; u < 16; u++) sB[kb + u][j] = wp[u];
            } else {
#pragma unroll
                for (int u = 0; u < 16; u++) sB[kb + u][j] = 0.0f;
            }
        }
        __syncthreads();
#pragma unroll
        for (int k = 0; k < BK; k++) {
            float a[4];
#pragma unroll
            for (int i = 0; i < 4; i++) a[i] = sA[ty * 4 + i][k];
            const float4 bv = *(const float4*)&sB[k][tx * 4];
            const float b[4] = {bv.x, bv.y, bv.z, bv.w};
#pragma unroll
            for (int i = 0; i < 4; i++)
#pragma unroll
                for (int jj = 0; jj < 4; jj++) acc[i][jj] += a[i] * b[jj];
        }
        __syncthreads();
    }

#pragma unroll
    for (int i = 0; i < 4; i++) {
        const int n = row0 + ty * 4 + i;
#pragma unroll
        for (int jj = 0; jj < 4; jj++) {
            const int j = tx * 4 + jj;
            if (j < NUM_CARDS) out[(size_t)n * NUM_CARDS + j] = acc[i][jj] + bias[j];
        }
    }
}

// ---------------- launch ----------------

static inline size_t align_up(size_t x, size_t a) { return (x + a - 1) & ~(a - 1); }

extern "C" void kernel_launch(void* const* d_in, const int* in_sizes, int n_in,
                              void* d_out, int out_size, void* d_ws, size_t ws_size,
                              hipStream_t stream) {
    const float* x   = (const float*)d_in[0];
    const float* Wl1 = (const float*)d_in[1];
    const float* bl1 = (const float*)d_in[2];
    const float* Wr1 = (const float*)d_in[3];
    const float* br1 = (const float*)d_in[4];
    const float* Wl2 = (const float*)d_in[5];
    const float* bl2 = (const float*)d_in[6];
    const float* Wr2 = (const float*)d_in[7];
    const float* br2 = (const float*)d_in[8];
    const float* Wo  = (const float*)d_in[9];
    const float* bo  = (const float*)d_in[10];
    const int* edge  = (const int*)d_in[11];   // [2, E] int32: src row then dst row
    const int* cards = (const int*)d_in[12];
    float* logits = (float*)d_out;

    const int* e_src = edge;
    const int* e_dst = edge + N_EDGES;

    char* w = (char*)d_ws;
    size_t off = 0;
    int* deg_i   = (int*)(w + off); off = align_up(off + N_NODES * 4, 512);
    int* cursor  = (int*)(w + off); off = align_up(off + N_NODES * 4, 512);
    int* row_off = (int*)(w + off); off = align_up(off + N_NODES * 4, 512);
    int* bsum    = (int*)(w + off); off = align_up(off + 128 * 4, 512);
    float* dinv  = (float*)(w + off); off = align_up(off + N_NODES * 4, 512);
    int* csr_src = (int*)(w + off); off = align_up(off + (size_t)N_EDGES * 4, 512);
    float* bufG  = (float*)(w + off); off = align_up(off + (size_t)N_NODES * HDIM * 4, 512);
    float* bufR  = (float*)(w + off); off = align_up(off + (size_t)N_NODES * HDIM * 4, 512);
    float* bufH  = (float*)(w + off); off = align_up(off + (size_t)N_NODES * HDIM * 4, 512);
    (void)ws_size; (void)n_in; (void)in_sizes; (void)out_size;

    hipMemsetAsync(deg_i, 0, N_NODES * 4, stream);
    hipMemsetAsync(cursor, 0, N_NODES * 4, stream);

    const int EB = (N_EDGES + 255) / 256;
    k_count<<<EB, 256, 0, stream>>>(e_dst, deg_i);
    k_scan1<<<98, 256, 0, stream>>>(deg_i, row_off, bsum);
    k_scan2<<<1, 128, 0, stream>>>(bsum, 98);
    k_scan3<<<(N_NODES + 255) / 256, 256, 0, stream>>>(row_off, bsum, deg_i, dinv);
    k_fill<<<EB, 256, 0, stream>>>(e_src, e_dst, row_off, cursor, csr_src);

    const int GB = N_NODES / BM;  // 3125
    // layer 1 (ld=129, cards column)
    k_gemm_dual<<<GB, 256, 0, stream>>>(x, cards, Wl1, Wr1, bl1, br1, bufG, bufR, 129, 1);
    k_agg<<<N_NODES / 4, 256, 0, stream>>>(bufG, bufR, row_off, deg_i, dinv, csr_src, bufH);
    // layer 2 (ld=128)
    k_gemm_dual<<<GB, 256, 0, stream>>>(bufH, nullptr, Wl2, Wr2, bl2, br2, bufG, bufR, 128, 0);
    k_agg<<<N_NODES / 4, 256, 0, stream>>>(bufG, bufR, row_off, deg_i, dinv, csr_src, bufH);
    // output
    k_gemm_out<<<GB, 256, 0, stream>>>(bufH, Wo, bo, logits);
}

// Round 2
// 584.195 us; speedup vs baseline: 1.3623x; 1.3623x over previous
//
#include <hip/hip_runtime.h>
#include <hip/hip_bf16.h>

#define N_NODES 100000
#define NPAD    100032            // padded to multiple of 64 (6252 row-tiles of 16)
#define N_EDGES 1600000
#define HDIM    128
#define KCH     4                 // K chunks of 32 (K = 128)
#define NUM_CARDS 110
#define NTILES  (NPAD / 16)       // 6252
#define GEMM_BLOCKS 1024

typedef __attribute__((ext_vector_type(8))) short bfrag;   // 8 bf16 = 4 VGPRs
typedef __attribute__((ext_vector_type(4))) float ffrag;   // 4 f32 acc

__device__ inline unsigned short f2bf(float f) {
    __hip_bfloat16 h = __float2bfloat16(f);
    unsigned short u; __builtin_memcpy(&u, &h, 2); return u;
}
__device__ inline float bf_lo(unsigned int u) {
    unsigned int v = u << 16; float f; __builtin_memcpy(&f, &v, 4); return f;
}
__device__ inline float bf_hi(unsigned int u) {
    unsigned int v = u & 0xffff0000u; float f; __builtin_memcpy(&f, &v, 4); return f;
}

// ---------------- CSR build (unchanged) ----------------

__global__ void k_count(const int* __restrict__ dst, int* __restrict__ deg) {
    int e = blockIdx.x * blockDim.x + threadIdx.x;
    if (e < N_EDGES) atomicAdd(&deg[dst[e]], 1);
}

__global__ void k_scan1(const int* __restrict__ deg, int* __restrict__ part,
                        int* __restrict__ bsum) {
    __shared__ int sdata[256];
    int b = blockIdx.x, t = threadIdx.x;
    int base = b * 1024 + t * 4;
    int v[4];
#pragma unroll
    for (int i = 0; i < 4; i++) {
        int n = base + i;
        v[i] = (n < N_NODES) ? deg[n] : 0;
    }
    int s0 = v[0] + v[1] + v[2] + v[3];
    sdata[t] = s0;
    __syncthreads();
    for (int off = 1; off < 256; off <<= 1) {
        int x = (t >= off) ? sdata[t - off] : 0;
        __syncthreads();
        sdata[t] += x;
        __syncthreads();
    }
    int run = sdata[t] - s0;
#pragma unroll
    for (int i = 0; i < 4; i++) {
        int n = base + i;
        if (n < N_NODES) part[n] = run;
        run += v[i];
    }
    if (t == 255) bsum[b] = sdata[255];
}

__global__ void k_scan2(int* __restrict__ bsum, int nb) {
    __shared__ int s[128];
    int t = threadIdx.x;
    int v = (t < nb) ? bsum[t] : 0;
    s[t] = v;
    __syncthreads();
    for (int off = 1; off < 128; off <<= 1) {
        int x = (t >= off) ? s[t - off] : 0;
        __syncthreads();
        s[t] += x;
        __syncthreads();
    }
    if (t < nb) bsum[t] = s[t] - v;
}

__global__ void k_scan3(int* __restrict__ row_off, const int* __restrict__ bsum,
                        const int* __restrict__ deg, float* __restrict__ deg_inv) {
    int n = blockIdx.x * blockDim.x + threadIdx.x;
    if (n < N_NODES) {
        row_off[n] += bsum[n >> 10];
        int d = deg[n];
        deg_inv[n] = (d > 0) ? 1.0f / (float)d : 0.0f;
    }
}

__global__ void k_fill(const int* __restrict__ src, const int* __restrict__ dst,
                       const int* __restrict__ row_off, int* __restrict__ cursor,
                       int* __restrict__ csr_src) {
    int e = blockIdx.x * blockDim.x + threadIdx.x;
    if (e < N_EDGES) {
        int d = dst[e];
        int p = row_off[d] + atomicAdd(&cursor[d], 1);
        csr_src[p] = src[e];
    }
}

// ---------------- prep: x -> bf16 (padded), cards -> float ----------------

__global__ void k_prep_x(const float* __restrict__ x, const int* __restrict__ cards,
                         unsigned short* __restrict__ xb, float* __restrict__ cardf) {
    int tid = blockIdx.x * 256 + threadIdx.x;      // NPAD*32 threads, 4 elems each
    int row = tid >> 5;
    int col4 = (tid & 31) * 4;
    if (row < NPAD) {
        float4 v = {0.f, 0.f, 0.f, 0.f};
        if (row < N_NODES) v = *(const float4*)&x[(size_t)row * HDIM + col4];
        unsigned int lo = (unsigned int)f2bf(v.x) | ((unsigned int)f2bf(v.y) << 16);
        unsigned int hi = (unsigned int)f2bf(v.z) | ((unsigned int)f2bf(v.w) << 16);
        uint2 p = {lo, hi};
        *(uint2*)&xb[(size_t)row * HDIM + col4] = p;
    }
    if (tid < NPAD) cardf[tid] = (tid < N_NODES) ? (float)cards[tid] : 0.f;
}

// ---------------- prep: weights -> bf16 concat layouts ----------------
// W1/W2: [256][128] bf16, rows 0-127 = WL (G), 128-255 = WR (R)
// bias1/2: [256] f32, zeros for G half, bl+br for R half
// wcard1: [256] f32 = card column (col 128) of Wl1 / Wr1
// Wob: [112][128] bf16 (rows >=110 zero), biaso: [112]

__global__ void k_prep_w(const float* __restrict__ Wl1, const float* __restrict__ Wr1,
                         const float* __restrict__ bl1, const float* __restrict__ br1,
                         const float* __restrict__ Wl2, const float* __restrict__ Wr2,
                         const float* __restrict__ bl2, const float* __restrict__ br2,
                         const float* __restrict__ Wo,  const float* __restrict__ bo,
                         unsigned short* __restrict__ W1, unsigned short* __restrict__ W2,
                         unsigned short* __restrict__ Wob,
                         float* __restrict__ bias1, float* __restrict__ bias2,
                         float* __restrict__ biaso, float* __restrict__ wcard1) {
    int j = threadIdx.x;  // 0..255
    {
        const float* src = (j < 128) ? &Wl1[(size_t)j * 129] : &Wr1[(size_t)(j - 128) * 129];
        for (int k = 0; k < HDIM; k++) W1[(size_t)j * HDIM + k] = f2bf(src[k]);
        wcard1[j] = src[HDIM];
        bias1[j] = (j < 128) ? 0.f : (bl1[j - 128] + br1[j - 128]);
    }
    {
        const float* src = (j < 128) ? &Wl2[(size_t)j * HDIM] : &Wr2[(size_t)(j - 128) * HDIM];
        for (int k = 0; k < HDIM; k++) W2[(size_t)j * HDIM + k] = f2bf(src[k]);
        bias2[j] = (j < 128) ? 0.f : (bl2[j - 128] + br2[j - 128]);
    }
    if (j < 112) {
        for (int k = 0; k < HDIM; k++)
            Wob[(size_t)j * HDIM + k] = (j < NUM_CARDS) ? f2bf(Wo[(size_t)j * HDIM + k]) : (unsigned short)0;
        biaso[j] = (j < NUM_CARDS) ? bo[j] : 0.f;
    }
}

// ---------------- dual GEMM, node-major output ----------------
// GR[node][j] = sum_k h[node][k]*Wcat[j][k] (+ card[node]*wcard[j]) + bias[j]
// mfma(A=W-frag, B=h-frag): D[m=j][n=node]; lane: node=lane&15, j rows quad*4+reg.
// Wave w owns col-units 4w..4w+3 (unit = 16 cols). Weights persist in registers.

__global__ __launch_bounds__(256) void k_gemm_dual(
    const unsigned short* __restrict__ A, const unsigned short* __restrict__ W,
    const float* __restrict__ bias, const float* __restrict__ wcard,
    const float* __restrict__ cardf, unsigned short* __restrict__ out,
    int has_card) {
    const int wave = threadIdx.x >> 6;
    const int lane = threadIdx.x & 63;
    const int m16 = lane & 15;
    const int quad = lane >> 4;
    const int u0 = wave * 4;

    bfrag wf[4][KCH];
    float bs[4][4], wc[4][4];
#pragma unroll
    for (int u = 0; u < 4; u++) {
        const int unit = u0 + u;
        const int j = unit * 16 + m16;
#pragma unroll
        for (int c = 0; c < KCH; c++)
            wf[u][c] = *(const bfrag*)&W[(size_t)j * HDIM + c * 32 + quad * 8];
#pragma unroll
        for (int r = 0; r < 4; r++) {
            const int jj = unit * 16 + quad * 4 + r;
            bs[u][r] = bias[jj];
            wc[u][r] = has_card ? wcard[jj] : 0.f;
        }
    }

    for (int tile = blockIdx.x; tile < NTILES; tile += GEMM_BLOCKS) {
        const int node = tile * 16 + m16;
        bfrag hf[KCH];
#pragma unroll
        for (int c = 0; c < KCH; c++)
            hf[c] = *(const bfrag*)&A[(size_t)node * HDIM + c * 32 + quad * 8];
        const float cv = has_card ? cardf[node] : 0.f;
#pragma unroll
        for (int u = 0; u < 4; u++) {
            ffrag acc = {0.f, 0.f, 0.f, 0.f};
#pragma unroll
            for (int c = 0; c < KCH; c++)
                acc = __builtin_amdgcn_mfma_f32_16x16x32_bf16(wf[u][c], hf[c], acc, 0, 0, 0);
            unsigned short o[4];
#pragma unroll
            for (int r = 0; r < 4; r++)
                o[r] = f2bf(acc[r] + bs[u][r] + cv * wc[u][r]);
            uint2 p = {(unsigned int)o[0] | ((unsigned int)o[1] << 16),
                       (unsigned int)o[2] | ((unsigned int)o[3] << 16)};
            // lane's node row, cols (u0+u)*16 + quad*4 .. +3
            *(uint2*)&out[(size_t)node * 256 + (u0 + u) * 16 + quad * 4] = p;
        }
    }
}

// ---------------- aggregate: h' = relu(mean(G[src]) + R), bf16 in/out ----------------
// GR row: cols 0-127 = G, 128-255 = R. One wave per node, 2 features/lane.

__global__ __launch_bounds__(256) void k_agg(
    const unsigned short* __restrict__ GR,
    const int* __restrict__ row_off, const int* __restrict__ deg,
    const float* __restrict__ deg_inv, const int* __restrict__ csr_src,
    unsigned short* __restrict__ outH) {
    const int wave = threadIdx.x >> 6;
    const int lane = threadIdx.x & 63;
    const int n = blockIdx.x * 4 + wave;
    if (n >= N_NODES) return;
    const int start = row_off[n];
    const int d = deg[n];
    const int f2 = lane * 2;                 // feature pair
    float sx0 = 0.f, sy0 = 0.f, sx1 = 0.f, sy1 = 0.f;
    float sx2 = 0.f, sy2 = 0.f, sx3 = 0.f, sy3 = 0.f;
    int j = 0;
    for (; j + 3 < d; j += 4) {
        const int a0 = csr_src[start + j];
        const int a1 = csr_src[start + j + 1];
        const int a2 = csr_src[start + j + 2];
        const int a3 = csr_src[start + j + 3];
        const unsigned int g0 = *(const unsigned int*)&GR[(size_t)a0 * 256 + f2];
        const unsigned int g1 = *(const unsigned int*)&GR[(size_t)a1 * 256 + f2];
        const unsigned int g2 = *(const unsigned int*)&GR[(size_t)a2 * 256 + f2];
        const unsigned int g3 = *(const unsigned int*)&GR[(size_t)a3 * 256 + f2];
        sx0 += bf_lo(g0); sy0 += bf_hi(g0);
        sx1 += bf_lo(g1); sy1 += bf_hi(g1);
        sx2 += bf_lo(g2); sy2 += bf_hi(g2);
        sx3 += bf_lo(g3); sy3 += bf_hi(g3);
    }
    for (; j < d; j++) {
        const int a0 = csr_src[start + j];
        const unsigned int g0 = *(const unsigned int*)&GR[(size_t)a0 * 256 + f2];
        sx0 += bf_lo(g0); sy0 += bf_hi(g0);
    }
    const float di = deg_inv[n];
    const unsigned int rr = *(const unsigned int*)&GR[(size_t)n * 256 + 128 + f2];
    const float ox = fmaxf((sx0 + sx1 + sx2 + sx3) * di + bf_lo(rr), 0.f);
    const float oy = fmaxf((sy0 + sy1 + sy2 + sy3) * di + bf_hi(rr), 0.f);
    unsigned int p = (unsigned int)f2bf(ox) | ((unsigned int)f2bf(oy) << 16);
    *(unsigned int*)&outH[(size_t)n * HDIM + f2] = p;
}

// ---------------- logits GEMM, j-major output ----------------
// mfma(A=h-frag, B=W-frag): D[m=node][n=j]; lane: j=lane&15, node rows quad*4+reg.
// 7 col-units (112 cols, guard j<110). Wave w owns units 2w, 2w+1 (unit 7 idle).

__global__ __launch_bounds__(256) void k_gemm_logits(
    const unsigned short* __restrict__ A, const unsigned short* __restrict__ W,
    const float* __restrict__ bias, float* __restrict__ out) {
    const int wave = threadIdx.x >> 6;
    const int lane = threadIdx.x & 63;
    const int m16 = lane & 15;
    const int quad = lane >> 4;
    const int u0 = wave * 2;

    bfrag wf[2][KCH];
    float bsj[2];
#pragma unroll
    for (int u = 0; u < 2; u++) {
        const int unit = u0 + u;
        const bool valid = unit < 7;
        const int j = (valid ? unit : 0) * 16 + m16;
#pragma unroll
        for (int c = 0; c < KCH; c++)
            wf[u][c] = *(const bfrag*)&W[(size_t)j * HDIM + c * 32 + quad * 8];
        bsj[u] = bias[j];
    }

    for (int tile = blockIdx.x; tile < NTILES; tile += GEMM_BLOCKS) {
        const int nodef = tile * 16 + m16;
        bfrag hf[KCH];
#pragma unroll
        for (int c = 0; c < KCH; c++)
            hf[c] = *(const bfrag*)&A[(size_t)nodef * HDIM + c * 32 + quad * 8];
#pragma unroll
        for (int u = 0; u < 2; u++) {
            const int unit = u0 + u;
            if (unit >= 7) break;
            ffrag acc = {0.f, 0.f, 0.f, 0.f};
#pragma unroll
            for (int c = 0; c < KCH; c++)
                acc = __builtin_amdgcn_mfma_f32_16x16x32_bf16(hf[c], wf[u][c], acc, 0, 0, 0);
            const int j = unit * 16 + m16;
            if (j < NUM_CARDS) {
#pragma unroll
                for (int r = 0; r < 4; r++) {
                    const int node = tile * 16 + quad * 4 + r;
                    if (node < N_NODES)
                        out[(size_t)node * NUM_CARDS + j] = acc[r] + bsj[u];
                }
            }
        }
    }
}

// ---------------- launch ----------------

static inline size_t align_up(size_t x, size_t a) { return (x + a - 1) & ~(a - 1); }

extern "C" void kernel_launch(void* const* d_in, const int* in_sizes, int n_in,
                              void* d_out, int out_size, void* d_ws, size_t ws_size,
                              hipStream_t stream) {
    const float* x   = (const float*)d_in[0];
    const float* Wl1 = (const float*)d_in[1];
    const float* bl1 = (const float*)d_in[2];
    const float* Wr1 = (const float*)d_in[3];
    const float* br1 = (const float*)d_in[4];
    const float* Wl2 = (const float*)d_in[5];
    const float* bl2 = (const float*)d_in[6];
    const float* Wr2 = (const float*)d_in[7];
    const float* br2 = (const float*)d_in[8];
    const float* Wo  = (const float*)d_in[9];
    const float* bo  = (const float*)d_in[10];
    const int* edge  = (const int*)d_in[11];
    const int* cards = (const int*)d_in[12];
    float* logits = (float*)d_out;

    const int* e_src = edge;
    const int* e_dst = edge + N_EDGES;

    char* w = (char*)d_ws;
    size_t off = 0;
    int* deg_i   = (int*)(w + off); off = align_up(off + N_NODES * 4, 512);
    int* cursor  = (int*)(w + off); off = align_up(off + N_NODES * 4, 512);
    int* row_off = (int*)(w + off); off = align_up(off + N_NODES * 4, 512);
    int* bsum    = (int*)(w + off); off = align_up(off + 128 * 4, 512);
    float* dinv  = (float*)(w + off); off = align_up(off + N_NODES * 4, 512);
    float* cardf = (float*)(w + off); off = align_up(off + (size_t)NPAD * 4, 512);
    int* csr_src = (int*)(w + off); off = align_up(off + (size_t)N_EDGES * 4, 512);
    unsigned short* xb  = (unsigned short*)(w + off); off = align_up(off + (size_t)NPAD * HDIM * 2, 512);
    unsigned short* GR  = (unsigned short*)(w + off); off = align_up(off + (size_t)NPAD * 256 * 2, 512);
    unsigned short* bufH = (unsigned short*)(w + off); off = align_up(off + (size_t)NPAD * HDIM * 2, 512);
    unsigned short* W1  = (unsigned short*)(w + off); off = align_up(off + 256 * HDIM * 2, 512);
    unsigned short* W2  = (unsigned short*)(w + off); off = align_up(off + 256 * HDIM * 2, 512);
    unsigned short* Wob = (unsigned short*)(w + off); off = align_up(off + 112 * HDIM * 2, 512);
    float* bias1 = (float*)(w + off); off = align_up(off + 256 * 4, 512);
    float* bias2 = (float*)(w + off); off = align_up(off + 256 * 4, 512);
    float* biaso = (float*)(w + off); off = align_up(off + 112 * 4, 512);
    float* wcard1 = (float*)(w + off); off = align_up(off + 256 * 4, 512);
    (void)ws_size; (void)n_in; (void)in_sizes; (void)out_size;

    hipMemsetAsync(deg_i, 0, N_NODES * 4, stream);
    hipMemsetAsync(cursor, 0, N_NODES * 4, stream);

    const int EB = (N_EDGES + 255) / 256;
    k_count<<<EB, 256, 0, stream>>>(e_dst, deg_i);
    k_scan1<<<98, 256, 0, stream>>>(deg_i, row_off, bsum);
    k_scan2<<<1, 128, 0, stream>>>(bsum, 98);
    k_scan3<<<(N_NODES + 255) / 256, 256, 0, stream>>>(row_off, bsum, deg_i, dinv);
    k_fill<<<EB, 256, 0, stream>>>(e_src, e_dst, row_off, cursor, csr_src);

    k_prep_x<<<NPAD * 32 / 256, 256, 0, stream>>>(x, cards, xb, cardf);
    k_prep_w<<<1, 256, 0, stream>>>(Wl1, Wr1, bl1, br1, Wl2, Wr2, bl2, br2, Wo, bo,
                                    W1, W2, Wob, bias1, bias2, biaso, wcard1);

    // layer 1
    k_gemm_dual<<<GEMM_BLOCKS, 256, 0, stream>>>(xb, W1, bias1, wcard1, cardf, GR, 1);
    k_agg<<<N_NODES / 4, 256, 0, stream>>>(GR, row_off, deg_i, dinv, csr_src, bufH);
    // layer 2
    k_gemm_dual<<<GEMM_BLOCKS, 256, 0, stream>>>(bufH, W2, bias2, wcard1, cardf, GR, 0);
    k_agg<<<N_NODES / 4, 256, 0, stream>>>(GR, row_off, deg_i, dinv, csr_src, bufH);
    // output
    k_gemm_logits<<<GEMM_BLOCKS, 256, 0, stream>>>(bufH, Wob, biaso, logits);
}

// Round 3
// 405.747 us; speedup vs baseline: 1.9614x; 1.4398x over previous
//
#include <hip/hip_runtime.h>
#include <hip/hip_bf16.h>

#define N_NODES 100000
#define N_EDGES 1600000
#define HDIM    128
#define KCH     4                  // K chunks of 32 (K = 128)
#define NUM_CARDS 110
#define NTILES  (N_NODES / 16)     // 6250 exactly
#define GEMM_BLOCKS 1024

#define NB      196                // node buckets: dst >> 9
#define MAXB    10240              // slack per bucket (avg 8192, 4 sigma ~ 8560)
#define PT      4096               // edges per partition block
#define PEPT    16                 // edges per thread in partition

typedef __attribute__((ext_vector_type(8))) short bfrag;   // 8 bf16 = 4 VGPRs
typedef __attribute__((ext_vector_type(4))) float ffrag;   // 4 f32 acc

__device__ inline unsigned short f2bf(float f) {
    __hip_bfloat16 h = __float2bfloat16(f);
    unsigned short u; __builtin_memcpy(&u, &h, 2); return u;
}
__device__ inline float bf_lo(unsigned int u) {
    unsigned int v = u << 16; float f; __builtin_memcpy(&f, &v, 4); return f;
}
__device__ inline float bf_hi(unsigned int u) {
    unsigned int v = u & 0xffff0000u; float f; __builtin_memcpy(&f, &v, 4); return f;
}

// ---------------- CSR build: bucketed counting sort ----------------
// pack: (dst & 511) << 17 | src   (src < 2^17)

__global__ __launch_bounds__(256) void k_partition(
    const int* __restrict__ src, const int* __restrict__ dst,
    int* __restrict__ bucket_cursor, unsigned int* __restrict__ part) {
    __shared__ int hist[NB];
    __shared__ int hcur[NB];
    const int t = threadIdx.x;
    const int base = blockIdx.x * PT;
    for (int i = t; i < NB; i += 256) hist[i] = 0;
    __syncthreads();
#pragma unroll
    for (int i = 0; i < PEPT; i++) {
        int e = base + i * 256 + t;
        if (e < N_EDGES) atomicAdd(&hist[dst[e] >> 9], 1);
    }
    __syncthreads();
    for (int b = t; b < NB; b += 256) {
        int h = hist[b];
        hcur[b] = h ? atomicAdd(&bucket_cursor[b], h) : 0;
    }
    __syncthreads();
#pragma unroll
    for (int i = 0; i < PEPT; i++) {
        int e = base + i * 256 + t;
        if (e < N_EDGES) {
            int d = dst[e];
            int b = d >> 9;
            int r = atomicAdd(&hcur[b], 1);
            if (r < MAXB)
                part[(size_t)b * MAXB + r] =
                    ((unsigned int)(d & 511) << 17) | (unsigned int)src[e];
        }
    }
}

__global__ void k_scan_buckets(const int* __restrict__ bucket_cursor,
                               int* __restrict__ bucket_base) {
    __shared__ int s[256];
    int t = threadIdx.x;
    int v = (t < NB) ? min(bucket_cursor[t], MAXB) : 0;
    s[t] = v;
    __syncthreads();
    for (int off = 1; off < 256; off <<= 1) {
        int x = (t >= off) ? s[t - off] : 0;
        __syncthreads();
        s[t] += x;
        __syncthreads();
    }
    if (t < NB) bucket_base[t] = s[t] - v;   // exclusive
}

__global__ __launch_bounds__(256) void k_bucket(
    const unsigned int* __restrict__ part, const int* __restrict__ bucket_cursor,
    const int* __restrict__ bucket_base, int* __restrict__ row_off,
    int* __restrict__ deg, float* __restrict__ deg_inv,
    int* __restrict__ csr_src) {
    __shared__ int degl[512];
    __shared__ int offl[512];
    __shared__ int curl[512];
    __shared__ int stmp[256];
    const int t = threadIdx.x;
    const int b = blockIdx.x;
    const int n0 = b << 9;
    const int nb = min(512, N_NODES - n0);
    const int cnt = min(bucket_cursor[b], MAXB);
    const int row0 = bucket_base[b];
    const unsigned int* pb = &part[(size_t)b * MAXB];

    degl[t] = 0; degl[t + 256] = 0;
    __syncthreads();
    for (int i = t; i < cnt; i += 256)
        atomicAdd(&degl[pb[i] >> 17], 1);
    __syncthreads();
    // exclusive scan of degl[512]
    const int a0 = degl[2 * t], a1 = degl[2 * t + 1];
    stmp[t] = a0 + a1;
    __syncthreads();
    for (int off = 1; off < 256; off <<= 1) {
        int x = (t >= off) ? stmp[t - off] : 0;
        __syncthreads();
        stmp[t] += x;
        __syncthreads();
    }
    const int excl = stmp[t] - (a0 + a1);
    offl[2 * t] = excl;       curl[2 * t] = excl;
    offl[2 * t + 1] = excl + a0; curl[2 * t + 1] = excl + a0;
    __syncthreads();
    for (int i = t; i < nb; i += 256) {
        int n = n0 + i;
        int d = degl[i];
        row_off[n] = row0 + offl[i];
        deg[n] = d;
        deg_inv[n] = (d > 0) ? 1.0f / (float)d : 0.0f;
    }
    for (int i = t; i < cnt; i += 256) {
        unsigned int pk = pb[i];
        int r = atomicAdd(&curl[pk >> 17], 1);
        csr_src[row0 + r] = (int)(pk & 0x1FFFFu);
    }
}

// ---------------- prep: weights -> bf16 concat layouts ----------------
// W1/W2: [256][128] bf16, rows 0-127 = WL (G), 128-255 = WR (R)
// bias: [256] f32 (0 for G half, bl+br for R half); wcard1: card column of W1

__global__ void k_prep_w(const float* __restrict__ Wl1, const float* __restrict__ Wr1,
                         const float* __restrict__ bl1, const float* __restrict__ br1,
                         const float* __restrict__ Wl2, const float* __restrict__ Wr2,
                         const float* __restrict__ bl2, const float* __restrict__ br2,
                         const float* __restrict__ Wo,  const float* __restrict__ bo,
                         unsigned short* __restrict__ W1, unsigned short* __restrict__ W2,
                         unsigned short* __restrict__ Wob,
                         float* __restrict__ bias1, float* __restrict__ bias2,
                         float* __restrict__ biaso, float* __restrict__ wcard1) {
    const int j = blockIdx.x;   // 0..255
    const int k = threadIdx.x;  // 0..127
    const float* s1 = (j < 128) ? &Wl1[(size_t)j * 129] : &Wr1[(size_t)(j - 128) * 129];
    W1[(size_t)j * HDIM + k] = f2bf(s1[k]);
    const float* s2 = (j < 128) ? &Wl2[(size_t)j * HDIM] : &Wr2[(size_t)(j - 128) * HDIM];
    W2[(size_t)j * HDIM + k] = f2bf(s2[k]);
    if (j < 112)
        Wob[(size_t)j * HDIM + k] = (j < NUM_CARDS) ? f2bf(Wo[(size_t)j * HDIM + k])
                                                    : (unsigned short)0;
    if (k == 0) {
        wcard1[j] = s1[HDIM];
        bias1[j] = (j < 128) ? 0.f : (bl1[j - 128] + br1[j - 128]);
        bias2[j] = (j < 128) ? 0.f : (bl2[j - 128] + br2[j - 128]);
        if (j < 112) biaso[j] = (j < NUM_CARDS) ? bo[j] : 0.f;
    }
}

// ---------------- dual GEMM, node-major output ----------------
// GR[node][j] = sum_k h[node][k]*Wcat[j][k] (+ card[node]*wcard[j]) + bias[j]
// mfma(A=W-frag, B=h-frag): lane: node=lane&15, j rows quad*4+reg.
// Wave w owns col-units 4w..4w+3 (unit = 16 cols). Weights persist in registers.

__global__ __launch_bounds__(256) void k_gemm_dual(
    const unsigned short* __restrict__ Ab, const float* __restrict__ Af,
    const int* __restrict__ cards,
    const unsigned short* __restrict__ W,
    const float* __restrict__ bias, const float* __restrict__ wcard,
    unsigned short* __restrict__ out, int layer1) {
    const int wave = threadIdx.x >> 6;
    const int lane = threadIdx.x & 63;
    const int m16 = lane & 15;
    const int quad = lane >> 4;
    const int u0 = wave * 4;

    bfrag wf[4][KCH];
    float bs[4][4], wc[4][4];
#pragma unroll
    for (int u = 0; u < 4; u++) {
        const int j = (u0 + u) * 16 + m16;
#pragma unroll
        for (int c = 0; c < KCH; c++)
            wf[u][c] = *(const bfrag*)&W[(size_t)j * HDIM + c * 32 + quad * 8];
#pragma unroll
        for (int r = 0; r < 4; r++) {
            const int jj = (u0 + u) * 16 + quad * 4 + r;
            bs[u][r] = bias[jj];
            wc[u][r] = layer1 ? wcard[jj] : 0.f;
        }
    }

    for (int tile = blockIdx.x; tile < NTILES; tile += GEMM_BLOCKS) {
        const int node = tile * 16 + m16;
        bfrag hf[KCH];
        float cv = 0.f;
        if (layer1) {
#pragma unroll
            for (int c = 0; c < KCH; c++) {
                const float4 p0 = *(const float4*)&Af[(size_t)node * HDIM + c * 32 + quad * 8];
                const float4 p1 = *(const float4*)&Af[(size_t)node * HDIM + c * 32 + quad * 8 + 4];
                bfrag h;
                h[0] = (short)f2bf(p0.x); h[1] = (short)f2bf(p0.y);
                h[2] = (short)f2bf(p0.z); h[3] = (short)f2bf(p0.w);
                h[4] = (short)f2bf(p1.x); h[5] = (short)f2bf(p1.y);
                h[6] = (short)f2bf(p1.z); h[7] = (short)f2bf(p1.w);
                hf[c] = h;
            }
            cv = (float)cards[node];
        } else {
#pragma unroll
            for (int c = 0; c < KCH; c++)
                hf[c] = *(const bfrag*)&Ab[(size_t)node * HDIM + c * 32 + quad * 8];
        }
#pragma unroll
        for (int u = 0; u < 4; u++) {
            ffrag acc = {0.f, 0.f, 0.f, 0.f};
#pragma unroll
            for (int c = 0; c < KCH; c++)
                acc = __builtin_amdgcn_mfma_f32_16x16x32_bf16(wf[u][c], hf[c], acc, 0, 0, 0);
            unsigned short o[4];
#pragma unroll
            for (int r = 0; r < 4; r++)
                o[r] = f2bf(acc[r] + bs[u][r] + cv * wc[u][r]);
            uint2 p = {(unsigned int)o[0] | ((unsigned int)o[1] << 16),
                       (unsigned int)o[2] | ((unsigned int)o[3] << 16)};
            *(uint2*)&out[(size_t)node * 256 + (u0 + u) * 16 + quad * 4] = p;
        }
    }
}

// ---------------- aggregate: h' = relu(mean(G[src]) + R), bf16 in/out ----------------
// One wave per node. 4 lane-groups of 16; group g handles edge j+g, lane-in-group
// l covers features [8l, 8l+8) via one uint4 (16 B). Cross-group shfl_xor reduce.

__global__ __launch_bounds__(256) void k_agg(
    const unsigned short* __restrict__ GR,
    const int* __restrict__ row_off, const int* __restrict__ deg,
    const float* __restrict__ deg_inv, const int* __restrict__ csr_src,
    unsigned short* __restrict__ outH) {
    const int wave = threadIdx.x >> 6;
    const int lane = threadIdx.x & 63;
    const int n = blockIdx.x * 4 + wave;
    const int g = lane >> 4;
    const int l = lane & 15;
    const int start = row_off[n];
    const int d = deg[n];
    const int fo = l * 8;   // feature offset (elements)

    float acc[8] = {0.f, 0.f, 0.f, 0.f, 0.f, 0.f, 0.f, 0.f};
    for (int j = 0; j < d; j += 4) {
        const int jj = j + g;
        uint4 gv = {0u, 0u, 0u, 0u};
        if (jj < d) {
            const int a = csr_src[start + jj];
            gv = *(const uint4*)&GR[(size_t)a * 256 + fo];
        }
        acc[0] += bf_lo(gv.x); acc[1] += bf_hi(gv.x);
        acc[2] += bf_lo(gv.y); acc[3] += bf_hi(gv.y);
        acc[4] += bf_lo(gv.z); acc[5] += bf_hi(gv.z);
        acc[6] += bf_lo(gv.w); acc[7] += bf_hi(gv.w);
    }
#pragma unroll
    for (int i = 0; i < 8; i++) {
        float v = acc[i];
        v += __shfl_xor(v, 16, 64);
        v += __shfl_xor(v, 32, 64);
        acc[i] = v;
    }
    if (g == 0) {
        const float di = deg_inv[n];
        const uint4 rv = *(const uint4*)&GR[(size_t)n * 256 + 128 + fo];
        const float r[8] = {bf_lo(rv.x), bf_hi(rv.x), bf_lo(rv.y), bf_hi(rv.y),
                            bf_lo(rv.z), bf_hi(rv.z), bf_lo(rv.w), bf_hi(rv.w)};
        unsigned short o[8];
#pragma unroll
        for (int i = 0; i < 8; i++)
            o[i] = f2bf(fmaxf(acc[i] * di + r[i], 0.f));
        uint4 p;
        p.x = (unsigned int)o[0] | ((unsigned int)o[1] << 16);
        p.y = (unsigned int)o[2] | ((unsigned int)o[3] << 16);
        p.z = (unsigned int)o[4] | ((unsigned int)o[5] << 16);
        p.w = (unsigned int)o[6] | ((unsigned int)o[7] << 16);
        *(uint4*)&outH[(size_t)n * HDIM + fo] = p;
    }
}

// ---------------- logits GEMM, j-major output ----------------
// mfma(A=h-frag, B=W-frag): lane: j=lane&15, node rows quad*4+reg.
// 7 col-units (112 cols, guard j<110). Wave w owns units 2w, 2w+1.

__global__ __launch_bounds__(256) void k_gemm_logits(
    const unsigned short* __restrict__ A, const unsigned short* __restrict__ W,
    const float* __restrict__ bias, float* __restrict__ out) {
    const int wave = threadIdx.x >> 6;
    const int lane = threadIdx.x & 63;
    const int m16 = lane & 15;
    const int quad = lane >> 4;
    const int u0 = wave * 2;

    bfrag wf[2][KCH];
    float bsj[2];
#pragma unroll
    for (int u = 0; u < 2; u++) {
        const int unit = u0 + u;
        const int j = (unit < 7 ? unit : 0) * 16 + m16;
#pragma unroll
        for (int c = 0; c < KCH; c++)
            wf[u][c] = *(const bfrag*)&W[(size_t)j * HDIM + c * 32 + quad * 8];
        bsj[u] = bias[j];
    }

    for (int tile = blockIdx.x; tile < NTILES; tile += GEMM_BLOCKS) {
        const int nodef = tile * 16 + m16;
        bfrag hf[KCH];
#pragma unroll
        for (int c = 0; c < KCH; c++)
            hf[c] = *(const bfrag*)&A[(size_t)nodef * HDIM + c * 32 + quad * 8];
#pragma unroll
        for (int u = 0; u < 2; u++) {
            const int unit = u0 + u;
            if (unit >= 7) break;
            ffrag acc = {0.f, 0.f, 0.f, 0.f};
#pragma unroll
            for (int c = 0; c < KCH; c++)
                acc = __builtin_amdgcn_mfma_f32_16x16x32_bf16(hf[c], wf[u][c], acc, 0, 0, 0);
            const int j = unit * 16 + m16;
            if (j < NUM_CARDS) {
#pragma unroll
                for (int r = 0; r < 4; r++) {
                    const int node = tile * 16 + quad * 4 + r;
                    out[(size_t)node * NUM_CARDS + j] = acc[r] + bsj[u];
                }
            }
        }
    }
}

// ---------------- launch ----------------

static inline size_t align_up(size_t x, size_t a) { return (x + a - 1) & ~(a - 1); }

extern "C" void kernel_launch(void* const* d_in, const int* in_sizes, int n_in,
                              void* d_out, int out_size, void* d_ws, size_t ws_size,
                              hipStream_t stream) {
    const float* x   = (const float*)d_in[0];
    const float* Wl1 = (const float*)d_in[1];
    const float* bl1 = (const float*)d_in[2];
    const float* Wr1 = (const float*)d_in[3];
    const float* br1 = (const float*)d_in[4];
    const float* Wl2 = (const float*)d_in[5];
    const float* bl2 = (const float*)d_in[6];
    const float* Wr2 = (const float*)d_in[7];
    const float* br2 = (const float*)d_in[8];
    const float* Wo  = (const float*)d_in[9];
    const float* bo  = (const float*)d_in[10];
    const int* edge  = (const int*)d_in[11];
    const int* cards = (const int*)d_in[12];
    float* logits = (float*)d_out;

    const int* e_src = edge;
    const int* e_dst = edge + N_EDGES;

    char* w = (char*)d_ws;
    size_t off = 0;
    int* bucket_cursor = (int*)(w + off); off = align_up(off + 256 * 4, 512);
    int* bucket_base   = (int*)(w + off); off = align_up(off + 256 * 4, 512);
    unsigned int* part = (unsigned int*)(w + off); off = align_up(off + (size_t)NB * MAXB * 4, 512);
    int* row_off = (int*)(w + off); off = align_up(off + N_NODES * 4, 512);
    int* deg_i   = (int*)(w + off); off = align_up(off + N_NODES * 4, 512);
    float* dinv  = (float*)(w + off); off = align_up(off + N_NODES * 4, 512);
    int* csr_src = (int*)(w + off); off = align_up(off + (size_t)N_EDGES * 4, 512);
    unsigned short* GR   = (unsigned short*)(w + off); off = align_up(off + (size_t)N_NODES * 256 * 2, 512);
    unsigned short* bufH = (unsigned short*)(w + off); off = align_up(off + (size_t)N_NODES * HDIM * 2, 512);
    unsigned short* W1   = (unsigned short*)(w + off); off = align_up(off + 256 * HDIM * 2, 512);
    unsigned short* W2   = (unsigned short*)(w + off); off = align_up(off + 256 * HDIM * 2, 512);
    unsigned short* Wob  = (unsigned short*)(w + off); off = align_up(off + 112 * HDIM * 2, 512);
    float* bias1  = (float*)(w + off); off = align_up(off + 256 * 4, 512);
    float* bias2  = (float*)(w + off); off = align_up(off + 256 * 4, 512);
    float* biaso  = (float*)(w + off); off = align_up(off + 112 * 4, 512);
    float* wcard1 = (float*)(w + off); off = align_up(off + 256 * 4, 512);
    (void)ws_size; (void)n_in; (void)in_sizes; (void)out_size;

    hipMemsetAsync(bucket_cursor, 0, 256 * 4, stream);
    k_prep_w<<<256, 128, 0, stream>>>(Wl1, Wr1, bl1, br1, Wl2, Wr2, bl2, br2, Wo, bo,
                                      W1, W2, Wob, bias1, bias2, biaso, wcard1);

    const int PBLK = (N_EDGES + PT - 1) / PT;   // 391
    k_partition<<<PBLK, 256, 0, stream>>>(e_src, e_dst, bucket_cursor, part);
    k_scan_buckets<<<1, 256, 0, stream>>>(bucket_cursor, bucket_base);
    k_bucket<<<NB, 256, 0, stream>>>(part, bucket_cursor, bucket_base,
                                     row_off, deg_i, dinv, csr_src);

    // layer 1 (reads f32 x directly, converts in-register)
    k_gemm_dual<<<GEMM_BLOCKS, 256, 0, stream>>>(nullptr, x, cards, W1, bias1, wcard1, GR, 1);
    k_agg<<<N_NODES / 4, 256, 0, stream>>>(GR, row_off, deg_i, dinv, csr_src, bufH);
    // layer 2
    k_gemm_dual<<<GEMM_BLOCKS, 256, 0, stream>>>(bufH, nullptr, nullptr, W2, bias2, wcard1, GR, 0);
    k_agg<<<N_NODES / 4, 256, 0, stream>>>(GR, row_off, deg_i, dinv, csr_src, bufH);
    // output
    k_gemm_logits<<<GEMM_BLOCKS, 256, 0, stream>>>(bufH, Wob, biaso, logits);
}

// Round 4
// 392.375 us; speedup vs baseline: 2.0283x; 1.0341x over previous
//
#include <hip/hip_runtime.h>
#include <hip/hip_bf16.h>

#define N_NODES 100000
#define N_EDGES 1600000
#define HDIM    128
#define KCH     4                  // K chunks of 32 (K = 128)
#define NUM_CARDS 110
#define NTILES  (N_NODES / 16)     // 6250 exactly
#define GEMM_BLOCKS 1024

#define NB      196                // node buckets: dst >> 9
#define MAXB    10240              // slack per bucket (avg 8192)
#define PT      4096               // edges per partition block
#define PEPT    16                 // edges per thread in partition

typedef __attribute__((ext_vector_type(8))) short bfrag;   // 8 bf16 = 4 VGPRs
typedef __attribute__((ext_vector_type(4))) float ffrag;   // 4 f32 acc
typedef __attribute__((ext_vector_type(2))) float f32x2;

__device__ inline unsigned short f2bf(float f) {
    __hip_bfloat16 h = __float2bfloat16(f);
    unsigned short u; __builtin_memcpy(&u, &h, 2); return u;
}
__device__ inline float bf_lo(unsigned int u) {
    unsigned int v = u << 16; float f; __builtin_memcpy(&f, &v, 4); return f;
}
__device__ inline float bf_hi(unsigned int u) {
    unsigned int v = u & 0xffff0000u; float f; __builtin_memcpy(&f, &v, 4); return f;
}

// ---------------- CSR build: bucketed counting sort ----------------
// pack: (dst & 511) << 17 | src   (src < 2^17)

__global__ __launch_bounds__(256) void k_partition(
    const int* __restrict__ src, const int* __restrict__ dst,
    int* __restrict__ bucket_cursor, unsigned int* __restrict__ part) {
    __shared__ int hist[NB];
    __shared__ int hcur[NB];
    const int t = threadIdx.x;
    const int base = blockIdx.x * PT;
    for (int i = t; i < NB; i += 256) hist[i] = 0;
    __syncthreads();
#pragma unroll
    for (int i = 0; i < PEPT; i++) {
        int e = base + i * 256 + t;
        if (e < N_EDGES) atomicAdd(&hist[dst[e] >> 9], 1);
    }
    __syncthreads();
    for (int b = t; b < NB; b += 256) {
        int h = hist[b];
        hcur[b] = h ? atomicAdd(&bucket_cursor[b], h) : 0;
    }
    __syncthreads();
#pragma unroll
    for (int i = 0; i < PEPT; i++) {
        int e = base + i * 256 + t;
        if (e < N_EDGES) {
            int d = dst[e];
            int b = d >> 9;
            int r = atomicAdd(&hcur[b], 1);
            if (r < MAXB)
                part[(size_t)b * MAXB + r] =
                    ((unsigned int)(d & 511) << 17) | (unsigned int)src[e];
        }
    }
}

__global__ void k_scan_buckets(const int* __restrict__ bucket_cursor,
                               int* __restrict__ bucket_base) {
    __shared__ int s[256];
    int t = threadIdx.x;
    int v = (t < NB) ? min(bucket_cursor[t], MAXB) : 0;
    s[t] = v;
    __syncthreads();
    for (int off = 1; off < 256; off <<= 1) {
        int x = (t >= off) ? s[t - off] : 0;
        __syncthreads();
        s[t] += x;
        __syncthreads();
    }
    if (t < NB) bucket_base[t] = s[t] - v;   // exclusive
}

__global__ __launch_bounds__(256) void k_bucket(
    const unsigned int* __restrict__ part, const int* __restrict__ bucket_cursor,
    const int* __restrict__ bucket_base, int* __restrict__ row_off,
    int* __restrict__ deg, float* __restrict__ deg_inv,
    int* __restrict__ csr_src) {
    __shared__ int degl[512];
    __shared__ int offl[512];
    __shared__ int curl[512];
    __shared__ int stmp[256];
    const int t = threadIdx.x;
    const int b = blockIdx.x;
    const int n0 = b << 9;
    const int nb = min(512, N_NODES - n0);
    const int cnt = min(bucket_cursor[b], MAXB);
    const int row0 = bucket_base[b];
    const unsigned int* pb = &part[(size_t)b * MAXB];

    degl[t] = 0; degl[t + 256] = 0;
    __syncthreads();
    for (int i = t; i < cnt; i += 256)
        atomicAdd(&degl[pb[i] >> 17], 1);
    __syncthreads();
    const int a0 = degl[2 * t], a1 = degl[2 * t + 1];
    stmp[t] = a0 + a1;
    __syncthreads();
    for (int off = 1; off < 256; off <<= 1) {
        int x = (t >= off) ? stmp[t - off] : 0;
        __syncthreads();
        stmp[t] += x;
        __syncthreads();
    }
    const int excl = stmp[t] - (a0 + a1);
    offl[2 * t] = excl;          curl[2 * t] = excl;
    offl[2 * t + 1] = excl + a0; curl[2 * t + 1] = excl + a0;
    __syncthreads();
    for (int i = t; i < nb; i += 256) {
        int n = n0 + i;
        int d = degl[i];
        row_off[n] = row0 + offl[i];
        deg[n] = d;
        deg_inv[n] = (d > 0) ? 1.0f / (float)d : 0.0f;
    }
    for (int i = t; i < cnt; i += 256) {
        unsigned int pk = pb[i];
        int r = atomicAdd(&curl[pk >> 17], 1);
        csr_src[row0 + r] = (int)(pk & 0x1FFFFu);
    }
}

// ---------------- prep: weights -> bf16 concat layouts ----------------

__global__ void k_prep_w(const float* __restrict__ Wl1, const float* __restrict__ Wr1,
                         const float* __restrict__ bl1, const float* __restrict__ br1,
                         const float* __restrict__ Wl2, const float* __restrict__ Wr2,
                         const float* __restrict__ bl2, const float* __restrict__ br2,
                         const float* __restrict__ Wo,  const float* __restrict__ bo,
                         unsigned short* __restrict__ W1, unsigned short* __restrict__ W2,
                         unsigned short* __restrict__ Wob,
                         float* __restrict__ bias1, float* __restrict__ bias2,
                         float* __restrict__ biaso, float* __restrict__ wcard1) {
    const int j = blockIdx.x;   // 0..255
    const int k = threadIdx.x;  // 0..127
    const float* s1 = (j < 128) ? &Wl1[(size_t)j * 129] : &Wr1[(size_t)(j - 128) * 129];
    W1[(size_t)j * HDIM + k] = f2bf(s1[k]);
    const float* s2 = (j < 128) ? &Wl2[(size_t)j * HDIM] : &Wr2[(size_t)(j - 128) * HDIM];
    W2[(size_t)j * HDIM + k] = f2bf(s2[k]);
    if (j < 112)
        Wob[(size_t)j * HDIM + k] = (j < NUM_CARDS) ? f2bf(Wo[(size_t)j * HDIM + k])
                                                    : (unsigned short)0;
    if (k == 0) {
        wcard1[j] = s1[HDIM];
        bias1[j] = (j < 128) ? 0.f : (bl1[j - 128] + br1[j - 128]);
        bias2[j] = (j < 128) ? 0.f : (bl2[j - 128] + br2[j - 128]);
        if (j < 112) biaso[j] = (j < NUM_CARDS) ? bo[j] : 0.f;
    }
}

// ---------------- dual GEMM: Gq (fp8 e4m3) + Rb (bf16) ----------------
// j = unit*16 + quad*4 + r over Wcat rows; units 0-7 -> G (fp8), 8-15 -> R (bf16).
// Waves 0,1 own G units; waves 2,3 own R units (wave-uniform epilogue).
// mfma(A=W-frag, B=h-frag): lane node = lane&15.

__global__ __launch_bounds__(256) void k_gemm_dual(
    const unsigned short* __restrict__ Ab, const float* __restrict__ Af,
    const int* __restrict__ cards,
    const unsigned short* __restrict__ W,
    const float* __restrict__ bias, const float* __restrict__ wcard,
    unsigned char* __restrict__ Gq, unsigned short* __restrict__ Rb,
    int layer1) {
    const int wave = threadIdx.x >> 6;
    const int lane = threadIdx.x & 63;
    const int m16 = lane & 15;
    const int quad = lane >> 4;
    const int u0 = wave * 4;
    const bool isG = (wave < 2);

    bfrag wf[4][KCH];
    float bs[4][4], wc[4][4];
#pragma unroll
    for (int u = 0; u < 4; u++) {
        const int j = (u0 + u) * 16 + m16;
#pragma unroll
        for (int c = 0; c < KCH; c++)
            wf[u][c] = *(const bfrag*)&W[(size_t)j * HDIM + c * 32 + quad * 8];
#pragma unroll
        for (int r = 0; r < 4; r++) {
            const int jj = (u0 + u) * 16 + quad * 4 + r;
            bs[u][r] = bias[jj];
            wc[u][r] = layer1 ? wcard[jj] : 0.f;
        }
    }

    for (int tile = blockIdx.x; tile < NTILES; tile += GEMM_BLOCKS) {
        const int node = tile * 16 + m16;
        bfrag hf[KCH];
        float cv = 0.f;
        if (layer1) {
#pragma unroll
            for (int c = 0; c < KCH; c++) {
                const float4 p0 = *(const float4*)&Af[(size_t)node * HDIM + c * 32 + quad * 8];
                const float4 p1 = *(const float4*)&Af[(size_t)node * HDIM + c * 32 + quad * 8 + 4];
                bfrag h;
                h[0] = (short)f2bf(p0.x); h[1] = (short)f2bf(p0.y);
                h[2] = (short)f2bf(p0.z); h[3] = (short)f2bf(p0.w);
                h[4] = (short)f2bf(p1.x); h[5] = (short)f2bf(p1.y);
                h[6] = (short)f2bf(p1.z); h[7] = (short)f2bf(p1.w);
                hf[c] = h;
            }
            cv = (float)cards[node];
        } else {
#pragma unroll
            for (int c = 0; c < KCH; c++)
                hf[c] = *(const bfrag*)&Ab[(size_t)node * HDIM + c * 32 + quad * 8];
        }
#pragma unroll
        for (int u = 0; u < 4; u++) {
            ffrag acc = {0.f, 0.f, 0.f, 0.f};
#pragma unroll
            for (int c = 0; c < KCH; c++)
                acc = __builtin_amdgcn_mfma_f32_16x16x32_bf16(wf[u][c], hf[c], acc, 0, 0, 0);
            float v[4];
#pragma unroll
            for (int r = 0; r < 4; r++)
                v[r] = acc[r] + bs[u][r] + cv * wc[u][r];
            if (isG) {
                // feature f = (u0+u)*16 + quad*4, 4 consecutive fp8 -> one uint
                int pk = __builtin_amdgcn_cvt_pk_fp8_f32(v[0], v[1], 0, false);
                pk = __builtin_amdgcn_cvt_pk_fp8_f32(v[2], v[3], pk, true);
                *(unsigned int*)&Gq[(size_t)node * HDIM + (u0 + u) * 16 + quad * 4] =
                    (unsigned int)pk;
            } else {
                unsigned short o[4];
#pragma unroll
                for (int r = 0; r < 4; r++) o[r] = f2bf(v[r]);
                uint2 p = {(unsigned int)o[0] | ((unsigned int)o[1] << 16),
                           (unsigned int)o[2] | ((unsigned int)o[3] << 16)};
                *(uint2*)&Rb[(size_t)node * HDIM + (u0 + u - 8) * 16 + quad * 4] = p;
            }
        }
    }
}

// ---------------- aggregate: h' = relu(mean(Gq[src]) + Rb), fp8 gather ----------------
// One wave per node. 4 lane-groups of 16; group g handles edge j+g; lane-in-group
// l covers features [8l, 8l+8) via one uint2 (8 fp8). Cross-group shfl_xor reduce.

__global__ __launch_bounds__(256) void k_agg(
    const unsigned char* __restrict__ Gq, const unsigned short* __restrict__ Rb,
    const int* __restrict__ row_off, const int* __restrict__ deg,
    const float* __restrict__ deg_inv, const int* __restrict__ csr_src,
    unsigned short* __restrict__ outH) {
    const int wave = threadIdx.x >> 6;
    const int lane = threadIdx.x & 63;
    const int n = blockIdx.x * 4 + wave;
    const int g = lane >> 4;
    const int l = lane & 15;
    const int start = row_off[n];
    const int d = deg[n];
    const int fo = l * 8;   // feature offset

    float acc[8] = {0.f, 0.f, 0.f, 0.f, 0.f, 0.f, 0.f, 0.f};
    for (int j = 0; j < d; j += 4) {
        const int jj = j + g;
        uint2 gv = {0u, 0u};
        if (jj < d) {
            const int a = csr_src[start + jj];
            gv = *(const uint2*)&Gq[(size_t)a * HDIM + fo];
        }
        const f32x2 d0 = __builtin_amdgcn_cvt_pk_f32_fp8((int)gv.x, false);
        const f32x2 d1 = __builtin_amdgcn_cvt_pk_f32_fp8((int)gv.x, true);
        const f32x2 d2 = __builtin_amdgcn_cvt_pk_f32_fp8((int)gv.y, false);
        const f32x2 d3 = __builtin_amdgcn_cvt_pk_f32_fp8((int)gv.y, true);
        acc[0] += d0.x; acc[1] += d0.y;
        acc[2] += d1.x; acc[3] += d1.y;
        acc[4] += d2.x; acc[5] += d2.y;
        acc[6] += d3.x; acc[7] += d3.y;
    }
#pragma unroll
    for (int i = 0; i < 8; i++) {
        float v = acc[i];
        v += __shfl_xor(v, 16, 64);
        v += __shfl_xor(v, 32, 64);
        acc[i] = v;
    }
    if (g == 0) {
        const float di = deg_inv[n];
        const uint4 rv = *(const uint4*)&Rb[(size_t)n * HDIM + fo];
        const float r[8] = {bf_lo(rv.x), bf_hi(rv.x), bf_lo(rv.y), bf_hi(rv.y),
                            bf_lo(rv.z), bf_hi(rv.z), bf_lo(rv.w), bf_hi(rv.w)};
        unsigned short o[8];
#pragma unroll
        for (int i = 0; i < 8; i++)
            o[i] = f2bf(fmaxf(acc[i] * di + r[i], 0.f));
        uint4 p;
        p.x = (unsigned int)o[0] | ((unsigned int)o[1] << 16);
        p.y = (unsigned int)o[2] | ((unsigned int)o[3] << 16);
        p.z = (unsigned int)o[4] | ((unsigned int)o[5] << 16);
        p.w = (unsigned int)o[6] | ((unsigned int)o[7] << 16);
        *(uint4*)&outH[(size_t)n * HDIM + fo] = p;
    }
}

// ---------------- logits GEMM, j-major output ----------------

__global__ __launch_bounds__(256) void k_gemm_logits(
    const unsigned short* __restrict__ A, const unsigned short* __restrict__ W,
    const float* __restrict__ bias, float* __restrict__ out) {
    const int wave = threadIdx.x >> 6;
    const int lane = threadIdx.x & 63;
    const int m16 = lane & 15;
    const int quad = lane >> 4;
    const int u0 = wave * 2;

    bfrag wf[2][KCH];
    float bsj[2];
#pragma unroll
    for (int u = 0; u < 2; u++) {
        const int unit = u0 + u;
        const int j = (unit < 7 ? unit : 0) * 16 + m16;
#pragma unroll
        for (int c = 0; c < KCH; c++)
            wf[u][c] = *(const bfrag*)&W[(size_t)j * HDIM + c * 32 + quad * 8];
        bsj[u] = bias[j];
    }

    for (int tile = blockIdx.x; tile < NTILES; tile += GEMM_BLOCKS) {
        const int nodef = tile * 16 + m16;
        bfrag hf[KCH];
#pragma unroll
        for (int c = 0; c < KCH; c++)
            hf[c] = *(const bfrag*)&A[(size_t)nodef * HDIM + c * 32 + quad * 8];
#pragma unroll
        for (int u = 0; u < 2; u++) {
            const int unit = u0 + u;
            if (unit >= 7) break;
            ffrag acc = {0.f, 0.f, 0.f, 0.f};
#pragma unroll
            for (int c = 0; c < KCH; c++)
                acc = __builtin_amdgcn_mfma_f32_16x16x32_bf16(hf[c], wf[u][c], acc, 0, 0, 0);
            const int j = unit * 16 + m16;
            if (j < NUM_CARDS) {
#pragma unroll
                for (int r = 0; r < 4; r++) {
                    const int node = tile * 16 + quad * 4 + r;
                    out[(size_t)node * NUM_CARDS + j] = acc[r] + bsj[u];
                }
            }
        }
    }
}

// ---------------- launch ----------------

static inline size_t align_up(size_t x, size_t a) { return (x + a - 1) & ~(a - 1); }

extern "C" void kernel_launch(void* const* d_in, const int* in_sizes, int n_in,
                              void* d_out, int out_size, void* d_ws, size_t ws_size,
                              hipStream_t stream) {
    const float* x   = (const float*)d_in[0];
    const float* Wl1 = (const float*)d_in[1];
    const float* bl1 = (const float*)d_in[2];
    const float* Wr1 = (const float*)d_in[3];
    const float* br1 = (const float*)d_in[4];
    const float* Wl2 = (const float*)d_in[5];
    const float* bl2 = (const float*)d_in[6];
    const float* Wr2 = (const float*)d_in[7];
    const float* br2 = (const float*)d_in[8];
    const float* Wo  = (const float*)d_in[9];
    const float* bo  = (const float*)d_in[10];
    const int* edge  = (const int*)d_in[11];
    const int* cards = (const int*)d_in[12];
    float* logits = (float*)d_out;

    const int* e_src = edge;
    const int* e_dst = edge + N_EDGES;

    char* w = (char*)d_ws;
    size_t off = 0;
    int* bucket_cursor = (int*)(w + off); off = align_up(off + 256 * 4, 512);
    int* bucket_base   = (int*)(w + off); off = align_up(off + 256 * 4, 512);
    unsigned int* part = (unsigned int*)(w + off); off = align_up(off + (size_t)NB * MAXB * 4, 512);
    int* row_off = (int*)(w + off); off = align_up(off + N_NODES * 4, 512);
    int* deg_i   = (int*)(w + off); off = align_up(off + N_NODES * 4, 512);
    float* dinv  = (float*)(w + off); off = align_up(off + N_NODES * 4, 512);
    int* csr_src = (int*)(w + off); off = align_up(off + (size_t)N_EDGES * 4, 512);
    unsigned char*  Gq   = (unsigned char*)(w + off);  off = align_up(off + (size_t)N_NODES * HDIM, 512);
    unsigned short* Rb   = (unsigned short*)(w + off); off = align_up(off + (size_t)N_NODES * HDIM * 2, 512);
    unsigned short* bufH = (unsigned short*)(w + off); off = align_up(off + (size_t)N_NODES * HDIM * 2, 512);
    unsigned short* W1   = (unsigned short*)(w + off); off = align_up(off + 256 * HDIM * 2, 512);
    unsigned short* W2   = (unsigned short*)(w + off); off = align_up(off + 256 * HDIM * 2, 512);
    unsigned short* Wob  = (unsigned short*)(w + off); off = align_up(off + 112 * HDIM * 2, 512);
    float* bias1  = (float*)(w + off); off = align_up(off + 256 * 4, 512);
    float* bias2  = (float*)(w + off); off = align_up(off + 256 * 4, 512);
    float* biaso  = (float*)(w + off); off = align_up(off + 112 * 4, 512);
    float* wcard1 = (float*)(w + off); off = align_up(off + 256 * 4, 512);
    (void)ws_size; (void)n_in; (void)in_sizes; (void)out_size;

    hipMemsetAsync(bucket_cursor, 0, 256 * 4, stream);
    k_prep_w<<<256, 128, 0, stream>>>(Wl1, Wr1, bl1, br1, Wl2, Wr2, bl2, br2, Wo, bo,
                                      W1, W2, Wob, bias1, bias2, biaso, wcard1);

    const int PBLK = (N_EDGES + PT - 1) / PT;   // 391
    k_partition<<<PBLK, 256, 0, stream>>>(e_src, e_dst, bucket_cursor, part);
    k_scan_buckets<<<1, 256, 0, stream>>>(bucket_cursor, bucket_base);
    k_bucket<<<NB, 256, 0, stream>>>(part, bucket_cursor, bucket_base,
                                     row_off, deg_i, dinv, csr_src);

    // layer 1 (reads f32 x directly, converts in-register)
    k_gemm_dual<<<GEMM_BLOCKS, 256, 0, stream>>>(nullptr, x, cards, W1, bias1, wcard1, Gq, Rb, 1);
    k_agg<<<N_NODES / 4, 256, 0, stream>>>(Gq, Rb, row_off, deg_i, dinv, csr_src, bufH);
    // layer 2
    k_gemm_dual<<<GEMM_BLOCKS, 256, 0, stream>>>(bufH, nullptr, nullptr, W2, bias2, wcard1, Gq, Rb, 0);
    k_agg<<<N_NODES / 4, 256, 0, stream>>>(Gq, Rb, row_off, deg_i, dinv, csr_src, bufH);
    // output
    k_gemm_logits<<<GEMM_BLOCKS, 256, 0, stream>>>(bufH, Wob, biaso, logits);
}

// Round 6
// 376.637 us; speedup vs baseline: 2.1130x; 1.0418x over previous
//
#include <hip/hip_runtime.h>
#include <hip/hip_bf16.h>

#define N_NODES 100000
#define N_EDGES 1600000
#define HDIM    128
#define KCH     4                  // K chunks of 32 (K = 128)
#define NUM_CARDS 110
#define NTILES  (N_NODES / 16)     // 6250 exactly
#define GEMM_BLOCKS 1024

#define NB      196                // node buckets: dst >> 9
#define MAXB    10240              // slack per bucket (avg 8192)
#define PT      4096               // edges per partition block
#define PEPT    16                 // edges per thread in partition

typedef __attribute__((ext_vector_type(8))) short bfrag;   // 8 bf16 = 4 VGPRs
typedef __attribute__((ext_vector_type(4))) float ffrag;   // 4 f32 acc
typedef __attribute__((ext_vector_type(2))) float f32x2;

__device__ inline unsigned short f2bf(float f) {
    __hip_bfloat16 h = __float2bfloat16(f);
    unsigned short u; __builtin_memcpy(&u, &h, 2); return u;
}
__device__ inline float bf_lo(unsigned int u) {
    unsigned int v = u << 16; float f; __builtin_memcpy(&f, &v, 4); return f;
}
__device__ inline float bf_hi(unsigned int u) {
    unsigned int v = u & 0xffff0000u; float f; __builtin_memcpy(&f, &v, 4); return f;
}

// ---------------- CSR build: bucketed counting sort ----------------
// pack: (dst & 511) << 17 | src   (src < 2^17)

__global__ __launch_bounds__(256) void k_partition(
    const int* __restrict__ src, const int* __restrict__ dst,
    int* __restrict__ bucket_cursor, unsigned int* __restrict__ part) {
    __shared__ int hist[NB];
    __shared__ int hcur[NB];
    const int t = threadIdx.x;
    const int base = blockIdx.x * PT;
    for (int i = t; i < NB; i += 256) hist[i] = 0;
    __syncthreads();
#pragma unroll
    for (int i = 0; i < PEPT; i++) {
        int e = base + i * 256 + t;
        if (e < N_EDGES) atomicAdd(&hist[dst[e] >> 9], 1);
    }
    __syncthreads();
    for (int b = t; b < NB; b += 256) {
        int h = hist[b];
        hcur[b] = h ? atomicAdd(&bucket_cursor[b], h) : 0;
    }
    __syncthreads();
#pragma unroll
    for (int i = 0; i < PEPT; i++) {
        int e = base + i * 256 + t;
        if (e < N_EDGES) {
            int d = dst[e];
            int b = d >> 9;
            int r = atomicAdd(&hcur[b], 1);
            if (r < MAXB)
                part[(size_t)b * MAXB + r] =
                    ((unsigned int)(d & 511) << 17) | (unsigned int)src[e];
        }
    }
}

__global__ void k_scan_buckets(const int* __restrict__ bucket_cursor,
                               int* __restrict__ bucket_base) {
    __shared__ int s[256];
    int t = threadIdx.x;
    int v = (t < NB) ? min(bucket_cursor[t], MAXB) : 0;
    s[t] = v;
    __syncthreads();
    for (int off = 1; off < 256; off <<= 1) {
        int x = (t >= off) ? s[t - off] : 0;
        __syncthreads();
        s[t] += x;
        __syncthreads();
    }
    if (t < NB) bucket_base[t] = s[t] - v;   // exclusive
}

__global__ __launch_bounds__(256) void k_bucket(
    const unsigned int* __restrict__ part, const int* __restrict__ bucket_cursor,
    const int* __restrict__ bucket_base, int* __restrict__ row_off,
    int* __restrict__ deg, float* __restrict__ deg_inv,
    int* __restrict__ csr_src) {
    __shared__ int degl[512];
    __shared__ int offl[512];
    __shared__ int curl[512];
    __shared__ int stmp[256];
    const int t = threadIdx.x;
    const int b = blockIdx.x;
    const int n0 = b << 9;
    const int nb = min(512, N_NODES - n0);
    const int cnt = min(bucket_cursor[b], MAXB);
    const int row0 = bucket_base[b];
    const unsigned int* pb = &part[(size_t)b * MAXB];

    degl[t] = 0; degl[t + 256] = 0;
    __syncthreads();
    for (int i = t; i < cnt; i += 256)
        atomicAdd(&degl[pb[i] >> 17], 1);
    __syncthreads();
    const int a0 = degl[2 * t], a1 = degl[2 * t + 1];
    stmp[t] = a0 + a1;
    __syncthreads();
    for (int off = 1; off < 256; off <<= 1) {
        int x = (t >= off) ? stmp[t - off] : 0;
        __syncthreads();
        stmp[t] += x;
        __syncthreads();
    }
    const int excl = stmp[t] - (a0 + a1);
    offl[2 * t] = excl;          curl[2 * t] = excl;
    offl[2 * t + 1] = excl + a0; curl[2 * t + 1] = excl + a0;
    __syncthreads();
    for (int i = t; i < nb; i += 256) {
        int n = n0 + i;
        int d = degl[i];
        row_off[n] = row0 + offl[i];
        deg[n] = d;
        deg_inv[n] = (d > 0) ? 1.0f / (float)d : 0.0f;
    }
    for (int i = t; i < cnt; i += 256) {
        unsigned int pk = pb[i];
        int r = atomicAdd(&curl[pk >> 17], 1);
        csr_src[row0 + r] = (int)(pk & 0x1FFFFu);
    }
}

// ---------------- prep: weights -> bf16 concat layouts ----------------

__global__ void k_prep_w(const float* __restrict__ Wl1, const float* __restrict__ Wr1,
                         const float* __restrict__ bl1, const float* __restrict__ br1,
                         const float* __restrict__ Wl2, const float* __restrict__ Wr2,
                         const float* __restrict__ bl2, const float* __restrict__ br2,
                         const float* __restrict__ Wo,  const float* __restrict__ bo,
                         unsigned short* __restrict__ W1, unsigned short* __restrict__ W2,
                         unsigned short* __restrict__ Wob,
                         float* __restrict__ bias1, float* __restrict__ bias2,
                         float* __restrict__ biaso, float* __restrict__ wcard1) {
    const int j = blockIdx.x;   // 0..255
    const int k = threadIdx.x;  // 0..127
    const float* s1 = (j < 128) ? &Wl1[(size_t)j * 129] : &Wr1[(size_t)(j - 128) * 129];
    W1[(size_t)j * HDIM + k] = f2bf(s1[k]);
    const float* s2 = (j < 128) ? &Wl2[(size_t)j * HDIM] : &Wr2[(size_t)(j - 128) * HDIM];
    W2[(size_t)j * HDIM + k] = f2bf(s2[k]);
    if (j < 112)
        Wob[(size_t)j * HDIM + k] = (j < NUM_CARDS) ? f2bf(Wo[(size_t)j * HDIM + k])
                                                    : (unsigned short)0;
    if (k == 0) {
        wcard1[j] = s1[HDIM];
        bias1[j] = (j < 128) ? 0.f : (bl1[j - 128] + br1[j - 128]);
        bias2[j] = (j < 128) ? 0.f : (bl2[j - 128] + br2[j - 128]);
        if (j < 112) biaso[j] = (j < NUM_CARDS) ? bo[j] : 0.f;
    }
}

// ---------------- dual GEMM: Gq (fp8 e4m3) + Rb (bf16) ----------------
// Waves 0,1 own G units (fp8 out); waves 2,3 own R units (bf16 out).

__global__ __launch_bounds__(256) void k_gemm_dual(
    const unsigned short* __restrict__ Ab, const float* __restrict__ Af,
    const int* __restrict__ cards,
    const unsigned short* __restrict__ W,
    const float* __restrict__ bias, const float* __restrict__ wcard,
    unsigned char* __restrict__ Gq, unsigned short* __restrict__ Rb,
    int layer1) {
    const int wave = threadIdx.x >> 6;
    const int lane = threadIdx.x & 63;
    const int m16 = lane & 15;
    const int quad = lane >> 4;
    const int u0 = wave * 4;
    const bool isG = (wave < 2);

    bfrag wf[4][KCH];
    float bs[4][4], wc[4][4];
#pragma unroll
    for (int u = 0; u < 4; u++) {
        const int j = (u0 + u) * 16 + m16;
#pragma unroll
        for (int c = 0; c < KCH; c++)
            wf[u][c] = *(const bfrag*)&W[(size_t)j * HDIM + c * 32 + quad * 8];
#pragma unroll
        for (int r = 0; r < 4; r++) {
            const int jj = (u0 + u) * 16 + quad * 4 + r;
            bs[u][r] = bias[jj];
            wc[u][r] = layer1 ? wcard[jj] : 0.f;
        }
    }

    for (int tile = blockIdx.x; tile < NTILES; tile += GEMM_BLOCKS) {
        const int node = tile * 16 + m16;
        bfrag hf[KCH];
        float cv = 0.f;
        if (layer1) {
#pragma unroll
            for (int c = 0; c < KCH; c++) {
                const float4 p0 = *(const float4*)&Af[(size_t)node * HDIM + c * 32 + quad * 8];
                const float4 p1 = *(const float4*)&Af[(size_t)node * HDIM + c * 32 + quad * 8 + 4];
                bfrag h;
                h[0] = (short)f2bf(p0.x); h[1] = (short)f2bf(p0.y);
                h[2] = (short)f2bf(p0.z); h[3] = (short)f2bf(p0.w);
                h[4] = (short)f2bf(p1.x); h[5] = (short)f2bf(p1.y);
                h[6] = (short)f2bf(p1.z); h[7] = (short)f2bf(p1.w);
                hf[c] = h;
            }
            cv = (float)cards[node];
        } else {
#pragma unroll
            for (int c = 0; c < KCH; c++)
                hf[c] = *(const bfrag*)&Ab[(size_t)node * HDIM + c * 32 + quad * 8];
        }
#pragma unroll
        for (int u = 0; u < 4; u++) {
            ffrag acc = {0.f, 0.f, 0.f, 0.f};
#pragma unroll
            for (int c = 0; c < KCH; c++)
                acc = __builtin_amdgcn_mfma_f32_16x16x32_bf16(wf[u][c], hf[c], acc, 0, 0, 0);
            float v[4];
#pragma unroll
            for (int r = 0; r < 4; r++)
                v[r] = acc[r] + bs[u][r] + cv * wc[u][r];
            if (isG) {
                int pk = __builtin_amdgcn_cvt_pk_fp8_f32(v[0], v[1], 0, false);
                pk = __builtin_amdgcn_cvt_pk_fp8_f32(v[2], v[3], pk, true);
                *(unsigned int*)&Gq[(size_t)node * HDIM + (u0 + u) * 16 + quad * 4] =
                    (unsigned int)pk;
            } else {
                unsigned short o[4];
#pragma unroll
                for (int r = 0; r < 4; r++) o[r] = f2bf(v[r]);
                uint2 p = {(unsigned int)o[0] | ((unsigned int)o[1] << 16),
                           (unsigned int)o[2] | ((unsigned int)o[3] << 16)};
                *(uint2*)&Rb[(size_t)node * HDIM + (u0 + u - 8) * 16 + quad * 4] = p;
            }
        }
    }
}

// ---------------- aggregate: h' = relu(mean(Gq[src]) + Rb) ----------------
// One wave per node. Lane preloads csr_src[start+lane] (deg<=64 common case),
// indices distributed via shfl executed at FULL exec mask (the j0 loop is
// wave-uniform; shfl inside a divergent branch reads inactive source lanes ->
// undefined, the R5 bug). 8 groups of 8 lanes: group g -> edge j0+g,
// lane-in-group l -> features [16l,16l+16) via one uint4 (16 fp8).

__global__ __launch_bounds__(256) void k_agg(
    const unsigned char* __restrict__ Gq, const unsigned short* __restrict__ Rb,
    const int* __restrict__ row_off, const int* __restrict__ deg,
    const float* __restrict__ deg_inv, const int* __restrict__ csr_src,
    unsigned short* __restrict__ outH) {
    const int wave = threadIdx.x >> 6;
    const int lane = threadIdx.x & 63;
    const int n = blockIdx.x * 4 + wave;
    const int g = lane >> 3;        // group 0..7 -> edge slot
    const int l = lane & 7;         // lane-in-group -> feature slice
    const int start = row_off[n];
    const int d = deg[n];
    const int fo = l * 16;          // fp8 feature offset (16 features, 16 B)

    // preload up to 64 edge indices into registers (one coalesced load)
    int myidx = (lane < d) ? csr_src[start + lane] : 0;

    float acc[16];
#pragma unroll
    for (int i = 0; i < 16; i++) acc[i] = 0.f;

    for (int j0 = 0; j0 < d; j0 += 8) {          // d is wave-uniform -> full exec
        const int jj = j0 + g;
        const int asrc = __shfl(myidx, jj & 63, 64);   // full-exec shfl (all lanes)
        uint4 gv = {0u, 0u, 0u, 0u};
        if (jj < d) {
            const int a = (jj < 64) ? asrc : csr_src[start + jj];
            gv = *(const uint4*)&Gq[(size_t)a * HDIM + fo];
        }
        const f32x2 d0 = __builtin_amdgcn_cvt_pk_f32_fp8((int)gv.x, false);
        const f32x2 d1 = __builtin_amdgcn_cvt_pk_f32_fp8((int)gv.x, true);
        const f32x2 d2 = __builtin_amdgcn_cvt_pk_f32_fp8((int)gv.y, false);
        const f32x2 d3 = __builtin_amdgcn_cvt_pk_f32_fp8((int)gv.y, true);
        const f32x2 d4 = __builtin_amdgcn_cvt_pk_f32_fp8((int)gv.z, false);
        const f32x2 d5 = __builtin_amdgcn_cvt_pk_f32_fp8((int)gv.z, true);
        const f32x2 d6 = __builtin_amdgcn_cvt_pk_f32_fp8((int)gv.w, false);
        const f32x2 d7 = __builtin_amdgcn_cvt_pk_f32_fp8((int)gv.w, true);
        acc[0] += d0.x;  acc[1] += d0.y;  acc[2] += d1.x;  acc[3] += d1.y;
        acc[4] += d2.x;  acc[5] += d2.y;  acc[6] += d3.x;  acc[7] += d3.y;
        acc[8] += d4.x;  acc[9] += d4.y;  acc[10] += d5.x; acc[11] += d5.y;
        acc[12] += d6.x; acc[13] += d6.y; acc[14] += d7.x; acc[15] += d7.y;
    }
#pragma unroll
    for (int i = 0; i < 16; i++) {
        float v = acc[i];
        v += __shfl_xor(v, 8, 64);
        v += __shfl_xor(v, 16, 64);
        v += __shfl_xor(v, 32, 64);
        acc[i] = v;
    }
    if (g == 0) {
        // lane l owns features [16l, 16l+16)
        const float di = deg_inv[n];
        const uint4 rv0 = *(const uint4*)&Rb[(size_t)n * HDIM + fo];
        const uint4 rv1 = *(const uint4*)&Rb[(size_t)n * HDIM + fo + 8];
        const float r[16] = {bf_lo(rv0.x), bf_hi(rv0.x), bf_lo(rv0.y), bf_hi(rv0.y),
                             bf_lo(rv0.z), bf_hi(rv0.z), bf_lo(rv0.w), bf_hi(rv0.w),
                             bf_lo(rv1.x), bf_hi(rv1.x), bf_lo(rv1.y), bf_hi(rv1.y),
                             bf_lo(rv1.z), bf_hi(rv1.z), bf_lo(rv1.w), bf_hi(rv1.w)};
        unsigned short o[16];
#pragma unroll
        for (int i = 0; i < 16; i++)
            o[i] = f2bf(fmaxf(acc[i] * di + r[i], 0.f));
        uint4 p0, p1;
        p0.x = (unsigned int)o[0] | ((unsigned int)o[1] << 16);
        p0.y = (unsigned int)o[2] | ((unsigned int)o[3] << 16);
        p0.z = (unsigned int)o[4] | ((unsigned int)o[5] << 16);
        p0.w = (unsigned int)o[6] | ((unsigned int)o[7] << 16);
        p1.x = (unsigned int)o[8] | ((unsigned int)o[9] << 16);
        p1.y = (unsigned int)o[10] | ((unsigned int)o[11] << 16);
        p1.z = (unsigned int)o[12] | ((unsigned int)o[13] << 16);
        p1.w = (unsigned int)o[14] | ((unsigned int)o[15] << 16);
        *(uint4*)&outH[(size_t)n * HDIM + fo] = p0;
        *(uint4*)&outH[(size_t)n * HDIM + fo + 8] = p1;
    }
}

// ---------------- logits GEMM, j-major output ----------------

__global__ __launch_bounds__(256) void k_gemm_logits(
    const unsigned short* __restrict__ A, const unsigned short* __restrict__ W,
    const float* __restrict__ bias, float* __restrict__ out) {
    const int wave = threadIdx.x >> 6;
    const int lane = threadIdx.x & 63;
    const int m16 = lane & 15;
    const int quad = lane >> 4;
    const int u0 = wave * 2;

    bfrag wf[2][KCH];
    float bsj[2];
#pragma unroll
    for (int u = 0; u < 2; u++) {
        const int unit = u0 + u;
        const int j = (unit < 7 ? unit : 0) * 16 + m16;
#pragma unroll
        for (int c = 0; c < KCH; c++)
            wf[u][c] = *(const bfrag*)&W[(size_t)j * HDIM + c * 32 + quad * 8];
        bsj[u] = bias[j];
    }

    for (int tile = blockIdx.x; tile < NTILES; tile += GEMM_BLOCKS) {
        const int nodef = tile * 16 + m16;
        bfrag hf[KCH];
#pragma unroll
        for (int c = 0; c < KCH; c++)
            hf[c] = *(const bfrag*)&A[(size_t)nodef * HDIM + c * 32 + quad * 8];
#pragma unroll
        for (int u = 0; u < 2; u++) {
            const int unit = u0 + u;
            if (unit >= 7) break;
            ffrag acc = {0.f, 0.f, 0.f, 0.f};
#pragma unroll
            for (int c = 0; c < KCH; c++)
                acc = __builtin_amdgcn_mfma_f32_16x16x32_bf16(hf[c], wf[u][c], acc, 0, 0, 0);
            const int j = unit * 16 + m16;
            if (j < NUM_CARDS) {
#pragma unroll
                for (int r = 0; r < 4; r++) {
                    const int node = tile * 16 + quad * 4 + r;
                    out[(size_t)node * NUM_CARDS + j] = acc[r] + bsj[u];
                }
            }
        }
    }
}

// ---------------- launch ----------------

static inline size_t align_up(size_t x, size_t a) { return (x + a - 1) & ~(a - 1); }

extern "C" void kernel_launch(void* const* d_in, const int* in_sizes, int n_in,
                              void* d_out, int out_size, void* d_ws, size_t ws_size,
                              hipStream_t stream) {
    const float* x   = (const float*)d_in[0];
    const float* Wl1 = (const float*)d_in[1];
    const float* bl1 = (const float*)d_in[2];
    const float* Wr1 = (const float*)d_in[3];
    const float* br1 = (const float*)d_in[4];
    const float* Wl2 = (const float*)d_in[5];
    const float* bl2 = (const float*)d_in[6];
    const float* Wr2 = (const float*)d_in[7];
    const float* br2 = (const float*)d_in[8];
    const float* Wo  = (const float*)d_in[9];
    const float* bo  = (const float*)d_in[10];
    const int* edge  = (const int*)d_in[11];
    const int* cards = (const int*)d_in[12];
    float* logits = (float*)d_out;

    const int* e_src = edge;
    const int* e_dst = edge + N_EDGES;

    char* w = (char*)d_ws;
    size_t off = 0;
    int* bucket_cursor = (int*)(w + off); off = align_up(off + 256 * 4, 512);
    int* bucket_base   = (int*)(w + off); off = align_up(off + 256 * 4, 512);
    unsigned int* part = (unsigned int*)(w + off); off = align_up(off + (size_t)NB * MAXB * 4, 512);
    int* row_off = (int*)(w + off); off = align_up(off + N_NODES * 4, 512);
    int* deg_i   = (int*)(w + off); off = align_up(off + N_NODES * 4, 512);
    float* dinv  = (float*)(w + off); off = align_up(off + N_NODES * 4, 512);
    int* csr_src = (int*)(w + off); off = align_up(off + (size_t)N_EDGES * 4, 512);
    unsigned char*  Gq   = (unsigned char*)(w + off);  off = align_up(off + (size_t)N_NODES * HDIM, 512);
    unsigned short* Rb   = (unsigned short*)(w + off); off = align_up(off + (size_t)N_NODES * HDIM * 2, 512);
    unsigned short* bufH = (unsigned short*)(w + off); off = align_up(off + (size_t)N_NODES * HDIM * 2, 512);
    unsigned short* W1   = (unsigned short*)(w + off); off = align_up(off + 256 * HDIM * 2, 512);
    unsigned short* W2   = (unsigned short*)(w + off); off = align_up(off + 256 * HDIM * 2, 512);
    unsigned short* Wob  = (unsigned short*)(w + off); off = align_up(off + 112 * HDIM * 2, 512);
    float* bias1  = (float*)(w + off); off = align_up(off + 256 * 4, 512);
    float* bias2  = (float*)(w + off); off = align_up(off + 256 * 4, 512);
    float* biaso  = (float*)(w + off); off = align_up(off + 112 * 4, 512);
    float* wcard1 = (float*)(w + off); off = align_up(off + 256 * 4, 512);
    (void)ws_size; (void)n_in; (void)in_sizes; (void)out_size;

    hipMemsetAsync(bucket_cursor, 0, 256 * 4, stream);
    k_prep_w<<<256, 128, 0, stream>>>(Wl1, Wr1, bl1, br1, Wl2, Wr2, bl2, br2, Wo, bo,
                                      W1, W2, Wob, bias1, bias2, biaso, wcard1);

    const int PBLK = (N_EDGES + PT - 1) / PT;   // 391
    k_partition<<<PBLK, 256, 0, stream>>>(e_src, e_dst, bucket_cursor, part);
    k_scan_buckets<<<1, 256, 0, stream>>>(bucket_cursor, bucket_base);
    k_bucket<<<NB, 256, 0, stream>>>(part, bucket_cursor, bucket_base,
                                     row_off, deg_i, dinv, csr_src);

    // layer 1 (reads f32 x directly, converts in-register)
    k_gemm_dual<<<GEMM_BLOCKS, 256, 0, stream>>>(nullptr, x, cards, W1, bias1, wcard1, Gq, Rb, 1);
    k_agg<<<N_NODES / 4, 256, 0, stream>>>(Gq, Rb, row_off, deg_i, dinv, csr_src, bufH);
    // layer 2
    k_gemm_dual<<<GEMM_BLOCKS, 256, 0, stream>>>(bufH, nullptr, nullptr, W2, bias2, wcard1, Gq, Rb, 0);
    k_agg<<<N_NODES / 4, 256, 0, stream>>>(Gq, Rb, row_off, deg_i, dinv, csr_src, bufH);
    // output
    k_gemm_logits<<<GEMM_BLOCKS, 256, 0, stream>>>(bufH, Wob, biaso, logits);
}

// Round 7
// 369.991 us; speedup vs baseline: 2.1510x; 1.0180x over previous
//
#include <hip/hip_runtime.h>
#include <hip/hip_bf16.h>

#define N_NODES 100000
#define N_EDGES 1600000
#define HDIM    128
#define KCH     4                  // K chunks of 32 (K = 128)
#define NUM_CARDS 110
#define NTILES  (N_NODES / 16)     // 6250 exactly
#define GEMM_BLOCKS 1024

#define NB      196                // node buckets: dst >> 9
#define MAXB    10240              // slack per bucket (avg 8192)
#define PT      4096               // edges per partition block
#define PEPT    16                 // edges per thread in partition

typedef __attribute__((ext_vector_type(8))) short bfrag;   // 8 bf16 = 4 VGPRs
typedef __attribute__((ext_vector_type(4))) float ffrag;   // 4 f32 acc
typedef __attribute__((ext_vector_type(2))) float f32x2;

__device__ inline unsigned short f2bf(float f) {
    __hip_bfloat16 h = __float2bfloat16(f);
    unsigned short u; __builtin_memcpy(&u, &h, 2); return u;
}
__device__ inline float bf_lo(unsigned int u) {
    unsigned int v = u << 16; float f; __builtin_memcpy(&f, &v, 4); return f;
}
__device__ inline float bf_hi(unsigned int u) {
    unsigned int v = u & 0xffff0000u; float f; __builtin_memcpy(&f, &v, 4); return f;
}

// ---------------- CSR build: bucketed counting sort ----------------
// pack: (dst & 511) << 17 | src   (src < 2^17)

__global__ __launch_bounds__(256) void k_partition(
    const int* __restrict__ src, const int* __restrict__ dst,
    int* __restrict__ bucket_cursor, unsigned int* __restrict__ part) {
    __shared__ int hist[NB];
    __shared__ int hcur[NB];
    const int t = threadIdx.x;
    const int base = blockIdx.x * PT;
    for (int i = t; i < NB; i += 256) hist[i] = 0;
    __syncthreads();
#pragma unroll
    for (int i = 0; i < PEPT; i++) {
        int e = base + i * 256 + t;
        if (e < N_EDGES) atomicAdd(&hist[dst[e] >> 9], 1);
    }
    __syncthreads();
    for (int b = t; b < NB; b += 256) {
        int h = hist[b];
        hcur[b] = h ? atomicAdd(&bucket_cursor[b], h) : 0;
    }
    __syncthreads();
#pragma unroll
    for (int i = 0; i < PEPT; i++) {
        int e = base + i * 256 + t;
        if (e < N_EDGES) {
            int d = dst[e];
            int b = d >> 9;
            int r = atomicAdd(&hcur[b], 1);
            if (r < MAXB)
                part[(size_t)b * MAXB + r] =
                    ((unsigned int)(d & 511) << 17) | (unsigned int)src[e];
        }
    }
}

// fixed-stride csr layout: bucket b owns csr_src[b*MAXB .. b*MAXB+cnt)
__global__ __launch_bounds__(256) void k_bucket(
    const unsigned int* __restrict__ part, const int* __restrict__ bucket_cursor,
    int* __restrict__ row_off, int* __restrict__ deg, float* __restrict__ deg_inv,
    int* __restrict__ csr_src) {
    __shared__ int degl[512];
    __shared__ int offl[512];
    __shared__ int curl[512];
    __shared__ int stmp[256];
    const int t = threadIdx.x;
    const int b = blockIdx.x;
    const int n0 = b << 9;
    const int nb = min(512, N_NODES - n0);
    const int cnt = min(bucket_cursor[b], MAXB);
    const int row0 = b * MAXB;
    const unsigned int* pb = &part[(size_t)b * MAXB];

    degl[t] = 0; degl[t + 256] = 0;
    __syncthreads();
    for (int i = t; i < cnt; i += 256)
        atomicAdd(&degl[pb[i] >> 17], 1);
    __syncthreads();
    const int a0 = degl[2 * t], a1 = degl[2 * t + 1];
    stmp[t] = a0 + a1;
    __syncthreads();
    for (int off = 1; off < 256; off <<= 1) {
        int x = (t >= off) ? stmp[t - off] : 0;
        __syncthreads();
        stmp[t] += x;
        __syncthreads();
    }
    const int excl = stmp[t] - (a0 + a1);
    offl[2 * t] = excl;          curl[2 * t] = excl;
    offl[2 * t + 1] = excl + a0; curl[2 * t + 1] = excl + a0;
    __syncthreads();
    for (int i = t; i < nb; i += 256) {
        int n = n0 + i;
        int d = degl[i];
        row_off[n] = row0 + offl[i];
        deg[n] = d;
        deg_inv[n] = (d > 0) ? 1.0f / (float)d : 0.0f;
    }
    for (int i = t; i < cnt; i += 256) {
        unsigned int pk = pb[i];
        int r = atomicAdd(&curl[pk >> 17], 1);
        csr_src[row0 + r] = (int)(pk & 0x1FFFFu);
    }
}

// ---------------- prep: weights -> bf16 concat layouts ----------------

__global__ void k_prep_w(const float* __restrict__ Wl1, const float* __restrict__ Wr1,
                         const float* __restrict__ bl1, const float* __restrict__ br1,
                         const float* __restrict__ Wl2, const float* __restrict__ Wr2,
                         const float* __restrict__ bl2, const float* __restrict__ br2,
                         const float* __restrict__ Wo,  const float* __restrict__ bo,
                         unsigned short* __restrict__ W1, unsigned short* __restrict__ W2,
                         unsigned short* __restrict__ Wob,
                         float* __restrict__ bias1, float* __restrict__ bias2,
                         float* __restrict__ biaso, float* __restrict__ wcard1) {
    const int j = blockIdx.x;   // 0..255
    const int k = threadIdx.x;  // 0..127
    const float* s1 = (j < 128) ? &Wl1[(size_t)j * 129] : &Wr1[(size_t)(j - 128) * 129];
    W1[(size_t)j * HDIM + k] = f2bf(s1[k]);
    const float* s2 = (j < 128) ? &Wl2[(size_t)j * HDIM] : &Wr2[(size_t)(j - 128) * HDIM];
    W2[(size_t)j * HDIM + k] = f2bf(s2[k]);
    if (j < 112)
        Wob[(size_t)j * HDIM + k] = (j < NUM_CARDS) ? f2bf(Wo[(size_t)j * HDIM + k])
                                                    : (unsigned short)0;
    if (k == 0) {
        wcard1[j] = s1[HDIM];
        bias1[j] = (j < 128) ? 0.f : (bl1[j - 128] + br1[j - 128]);
        bias2[j] = (j < 128) ? 0.f : (bl2[j - 128] + br2[j - 128]);
        if (j < 112) biaso[j] = (j < NUM_CARDS) ? bo[j] : 0.f;
    }
}

// ---------------- dual GEMM: Gq (fp8 e4m3) + Rb (bf16) ----------------
// Waves 0,1 own G units (fp8 out); waves 2,3 own R units (bf16 out).

__global__ __launch_bounds__(256) void k_gemm_dual(
    const unsigned short* __restrict__ Ab, const float* __restrict__ Af,
    const int* __restrict__ cards,
    const unsigned short* __restrict__ W,
    const float* __restrict__ bias, const float* __restrict__ wcard,
    unsigned char* __restrict__ Gq, unsigned short* __restrict__ Rb,
    int layer1) {
    const int wave = threadIdx.x >> 6;
    const int lane = threadIdx.x & 63;
    const int m16 = lane & 15;
    const int quad = lane >> 4;
    const int u0 = wave * 4;
    const bool isG = (wave < 2);

    bfrag wf[4][KCH];
    float bs[4][4], wc[4][4];
#pragma unroll
    for (int u = 0; u < 4; u++) {
        const int j = (u0 + u) * 16 + m16;
#pragma unroll
        for (int c = 0; c < KCH; c++)
            wf[u][c] = *(const bfrag*)&W[(size_t)j * HDIM + c * 32 + quad * 8];
#pragma unroll
        for (int r = 0; r < 4; r++) {
            const int jj = (u0 + u) * 16 + quad * 4 + r;
            bs[u][r] = bias[jj];
            wc[u][r] = layer1 ? wcard[jj] : 0.f;
        }
    }

    for (int tile = blockIdx.x; tile < NTILES; tile += GEMM_BLOCKS) {
        const int node = tile * 16 + m16;
        bfrag hf[KCH];
        float cv = 0.f;
        if (layer1) {
#pragma unroll
            for (int c = 0; c < KCH; c++) {
                const float4 p0 = *(const float4*)&Af[(size_t)node * HDIM + c * 32 + quad * 8];
                const float4 p1 = *(const float4*)&Af[(size_t)node * HDIM + c * 32 + quad * 8 + 4];
                bfrag h;
                h[0] = (short)f2bf(p0.x); h[1] = (short)f2bf(p0.y);
                h[2] = (short)f2bf(p0.z); h[3] = (short)f2bf(p0.w);
                h[4] = (short)f2bf(p1.x); h[5] = (short)f2bf(p1.y);
                h[6] = (short)f2bf(p1.z); h[7] = (short)f2bf(p1.w);
                hf[c] = h;
            }
            cv = (float)cards[node];
        } else {
#pragma unroll
            for (int c = 0; c < KCH; c++)
                hf[c] = *(const bfrag*)&Ab[(size_t)node * HDIM + c * 32 + quad * 8];
        }
#pragma unroll
        for (int u = 0; u < 4; u++) {
            ffrag acc = {0.f, 0.f, 0.f, 0.f};
#pragma unroll
            for (int c = 0; c < KCH; c++)
                acc = __builtin_amdgcn_mfma_f32_16x16x32_bf16(wf[u][c], hf[c], acc, 0, 0, 0);
            float v[4];
#pragma unroll
            for (int r = 0; r < 4; r++)
                v[r] = acc[r] + bs[u][r] + cv * wc[u][r];
            if (isG) {
                int pk = __builtin_amdgcn_cvt_pk_fp8_f32(v[0], v[1], 0, false);
                pk = __builtin_amdgcn_cvt_pk_fp8_f32(v[2], v[3], pk, true);
                *(unsigned int*)&Gq[(size_t)node * HDIM + (u0 + u) * 16 + quad * 4] =
                    (unsigned int)pk;
            } else {
                unsigned short o[4];
#pragma unroll
                for (int r = 0; r < 4; r++) o[r] = f2bf(v[r]);
                uint2 p = {(unsigned int)o[0] | ((unsigned int)o[1] << 16),
                           (unsigned int)o[2] | ((unsigned int)o[3] << 16)};
                *(uint2*)&Rb[(size_t)node * HDIM + (u0 + u - 8) * 16 + quad * 4] = p;
            }
        }
    }
}

// ---------------- aggregate: h' = relu(mean(Gq[src]) + Rb) ----------------
// One wave per node. Lane preloads csr_src byte-offset; indices via full-exec
// shfl (R5 lesson: never shfl under divergence). 8 groups x 8 lanes; lane
// covers 16 fp8 features via one uint4. Software-pipelined cur/nxt loads
// (vmcnt(1) overlap). Packed f32x2 accumulate + reduce (v_pk_add_f32).

__global__ __launch_bounds__(256) void k_agg(
    const unsigned char* __restrict__ Gq, const unsigned short* __restrict__ Rb,
    const int* __restrict__ row_off, const int* __restrict__ deg,
    const float* __restrict__ deg_inv, const int* __restrict__ csr_src,
    unsigned short* __restrict__ outH) {
    const int wave = threadIdx.x >> 6;
    const int lane = threadIdx.x & 63;
    const int n = blockIdx.x * 4 + wave;
    const int g = lane >> 3;        // group 0..7 -> edge slot
    const int l = lane & 7;         // lane-in-group -> feature slice
    const int start = row_off[n];
    const int d = deg[n];
    const int fo = l * 16;          // fp8 feature offset (16 features, 16 B)

    // preload up to 64 edge byte-offsets (one coalesced load, pre-scaled)
    int myoff = 0;
    if (lane < d) myoff = csr_src[start + lane] * HDIM;

    // prefetch the R row early (only g==0 lanes need it)
    uint4 rv0 = {0u, 0u, 0u, 0u}, rv1 = {0u, 0u, 0u, 0u};
    if (g == 0) {
        rv0 = *(const uint4*)&Rb[(size_t)n * HDIM + l * 16];
        rv1 = *(const uint4*)&Rb[(size_t)n * HDIM + l * 16 + 8];
    }

    f32x2 acc2[8];
#pragma unroll
    for (int i = 0; i < 8; i++) acc2[i] = (f32x2){0.f, 0.f};

    const int iters = (d + 7) >> 3;        // wave-uniform

    uint4 cur = {0u, 0u, 0u, 0u};
    {
        const int off0 = __shfl(myoff, g, 64);     // full-exec shfl
        if (g < d) cur = *(const uint4*)&Gq[(size_t)(unsigned)off0 + fo];
    }
    for (int i = 1; i < iters; i++) {
        const int jj = i * 8 + g;
        const int offn = __shfl(myoff, jj & 63, 64);   // full-exec shfl
        uint4 nxt = {0u, 0u, 0u, 0u};
        if (jj < d) {
            const int o = (jj < 64) ? offn : csr_src[start + jj] * HDIM;
            nxt = *(const uint4*)&Gq[(size_t)(unsigned)o + fo];
        }
        // consume cur (waits vmcnt(1): nxt stays in flight)
        acc2[0] += __builtin_amdgcn_cvt_pk_f32_fp8((int)cur.x, false);
        acc2[1] += __builtin_amdgcn_cvt_pk_f32_fp8((int)cur.x, true);
        acc2[2] += __builtin_amdgcn_cvt_pk_f32_fp8((int)cur.y, false);
        acc2[3] += __builtin_amdgcn_cvt_pk_f32_fp8((int)cur.y, true);
        acc2[4] += __builtin_amdgcn_cvt_pk_f32_fp8((int)cur.z, false);
        acc2[5] += __builtin_amdgcn_cvt_pk_f32_fp8((int)cur.z, true);
        acc2[6] += __builtin_amdgcn_cvt_pk_f32_fp8((int)cur.w, false);
        acc2[7] += __builtin_amdgcn_cvt_pk_f32_fp8((int)cur.w, true);
        cur = nxt;
    }
    acc2[0] += __builtin_amdgcn_cvt_pk_f32_fp8((int)cur.x, false);
    acc2[1] += __builtin_amdgcn_cvt_pk_f32_fp8((int)cur.x, true);
    acc2[2] += __builtin_amdgcn_cvt_pk_f32_fp8((int)cur.y, false);
    acc2[3] += __builtin_amdgcn_cvt_pk_f32_fp8((int)cur.y, true);
    acc2[4] += __builtin_amdgcn_cvt_pk_f32_fp8((int)cur.z, false);
    acc2[5] += __builtin_amdgcn_cvt_pk_f32_fp8((int)cur.z, true);
    acc2[6] += __builtin_amdgcn_cvt_pk_f32_fp8((int)cur.w, false);
    acc2[7] += __builtin_amdgcn_cvt_pk_f32_fp8((int)cur.w, true);

    // reduce over the 8 groups (packed adds)
#pragma unroll
    for (int i = 0; i < 8; i++) {
        f32x2 v = acc2[i];
        f32x2 t;
        t.x = __shfl_xor(v.x, 8, 64);  t.y = __shfl_xor(v.y, 8, 64);  v += t;
        t.x = __shfl_xor(v.x, 16, 64); t.y = __shfl_xor(v.y, 16, 64); v += t;
        t.x = __shfl_xor(v.x, 32, 64); t.y = __shfl_xor(v.y, 32, 64); v += t;
        acc2[i] = v;
    }
    if (g == 0) {
        const float di = deg_inv[n];
        const float r[16] = {bf_lo(rv0.x), bf_hi(rv0.x), bf_lo(rv0.y), bf_hi(rv0.y),
                             bf_lo(rv0.z), bf_hi(rv0.z), bf_lo(rv0.w), bf_hi(rv0.w),
                             bf_lo(rv1.x), bf_hi(rv1.x), bf_lo(rv1.y), bf_hi(rv1.y),
                             bf_lo(rv1.z), bf_hi(rv1.z), bf_lo(rv1.w), bf_hi(rv1.w)};
        unsigned short o[16];
#pragma unroll
        for (int i = 0; i < 8; i++) {
            o[2 * i]     = f2bf(fmaxf(acc2[i].x * di + r[2 * i], 0.f));
            o[2 * i + 1] = f2bf(fmaxf(acc2[i].y * di + r[2 * i + 1], 0.f));
        }
        uint4 p0, p1;
        p0.x = (unsigned int)o[0] | ((unsigned int)o[1] << 16);
        p0.y = (unsigned int)o[2] | ((unsigned int)o[3] << 16);
        p0.z = (unsigned int)o[4] | ((unsigned int)o[5] << 16);
        p0.w = (unsigned int)o[6] | ((unsigned int)o[7] << 16);
        p1.x = (unsigned int)o[8] | ((unsigned int)o[9] << 16);
        p1.y = (unsigned int)o[10] | ((unsigned int)o[11] << 16);
        p1.z = (unsigned int)o[12] | ((unsigned int)o[13] << 16);
        p1.w = (unsigned int)o[14] | ((unsigned int)o[15] << 16);
        *(uint4*)&outH[(size_t)n * HDIM + l * 16] = p0;
        *(uint4*)&outH[(size_t)n * HDIM + l * 16 + 8] = p1;
    }
}

// ---------------- logits GEMM, j-major output ----------------

__global__ __launch_bounds__(256) void k_gemm_logits(
    const unsigned short* __restrict__ A, const unsigned short* __restrict__ W,
    const float* __restrict__ bias, float* __restrict__ out) {
    const int wave = threadIdx.x >> 6;
    const int lane = threadIdx.x & 63;
    const int m16 = lane & 15;
    const int quad = lane >> 4;
    const int u0 = wave * 2;

    bfrag wf[2][KCH];
    float bsj[2];
#pragma unroll
    for (int u = 0; u < 2; u++) {
        const int unit = u0 + u;
        const int j = (unit < 7 ? unit : 0) * 16 + m16;
#pragma unroll
        for (int c = 0; c < KCH; c++)
            wf[u][c] = *(const bfrag*)&W[(size_t)j * HDIM + c * 32 + quad * 8];
        bsj[u] = bias[j];
    }

    for (int tile = blockIdx.x; tile < NTILES; tile += GEMM_BLOCKS) {
        const int nodef = tile * 16 + m16;
        bfrag hf[KCH];
#pragma unroll
        for (int c = 0; c < KCH; c++)
            hf[c] = *(const bfrag*)&A[(size_t)nodef * HDIM + c * 32 + quad * 8];
#pragma unroll
        for (int u = 0; u < 2; u++) {
            const int unit = u0 + u;
            if (unit >= 7) break;
            ffrag acc = {0.f, 0.f, 0.f, 0.f};
#pragma unroll
            for (int c = 0; c < KCH; c++)
                acc = __builtin_amdgcn_mfma_f32_16x16x32_bf16(hf[c], wf[u][c], acc, 0, 0, 0);
            const int j = unit * 16 + m16;
            if (j < NUM_CARDS) {
#pragma unroll
                for (int r = 0; r < 4; r++) {
                    const int node = tile * 16 + quad * 4 + r;
                    out[(size_t)node * NUM_CARDS + j] = acc[r] + bsj[u];
                }
            }
        }
    }
}

// ---------------- launch ----------------

static inline size_t align_up(size_t x, size_t a) { return (x + a - 1) & ~(a - 1); }

extern "C" void kernel_launch(void* const* d_in, const int* in_sizes, int n_in,
                              void* d_out, int out_size, void* d_ws, size_t ws_size,
                              hipStream_t stream) {
    const float* x   = (const float*)d_in[0];
    const float* Wl1 = (const float*)d_in[1];
    const float* bl1 = (const float*)d_in[2];
    const float* Wr1 = (const float*)d_in[3];
    const float* br1 = (const float*)d_in[4];
    const float* Wl2 = (const float*)d_in[5];
    const float* bl2 = (const float*)d_in[6];
    const float* Wr2 = (const float*)d_in[7];
    const float* br2 = (const float*)d_in[8];
    const float* Wo  = (const float*)d_in[9];
    const float* bo  = (const float*)d_in[10];
    const int* edge  = (const int*)d_in[11];
    const int* cards = (const int*)d_in[12];
    float* logits = (float*)d_out;

    const int* e_src = edge;
    const int* e_dst = edge + N_EDGES;

    char* w = (char*)d_ws;
    size_t off = 0;
    int* bucket_cursor = (int*)(w + off); off = align_up(off + 256 * 4, 512);
    unsigned int* part = (unsigned int*)(w + off); off = align_up(off + (size_t)NB * MAXB * 4, 512);
    int* row_off = (int*)(w + off); off = align_up(off + N_NODES * 4, 512);
    int* deg_i   = (int*)(w + off); off = align_up(off + N_NODES * 4, 512);
    float* dinv  = (float*)(w + off); off = align_up(off + N_NODES * 4, 512);
    int* csr_src = (int*)(w + off); off = align_up(off + (size_t)NB * MAXB * 4, 512);
    unsigned char*  Gq   = (unsigned char*)(w + off);  off = align_up(off + (size_t)N_NODES * HDIM, 512);
    unsigned short* Rb   = (unsigned short*)(w + off); off = align_up(off + (size_t)N_NODES * HDIM * 2, 512);
    unsigned short* bufH = (unsigned short*)(w + off); off = align_up(off + (size_t)N_NODES * HDIM * 2, 512);
    unsigned short* W1   = (unsigned short*)(w + off); off = align_up(off + 256 * HDIM * 2, 512);
    unsigned short* W2   = (unsigned short*)(w + off); off = align_up(off + 256 * HDIM * 2, 512);
    unsigned short* Wob  = (unsigned short*)(w + off); off = align_up(off + 112 * HDIM * 2, 512);
    float* bias1  = (float*)(w + off); off = align_up(off + 256 * 4, 512);
    float* bias2  = (float*)(w + off); off = align_up(off + 256 * 4, 512);
    float* biaso  = (float*)(w + off); off = align_up(off + 112 * 4, 512);
    float* wcard1 = (float*)(w + off); off = align_up(off + 256 * 4, 512);
    (void)ws_size; (void)n_in; (void)in_sizes; (void)out_size;

    hipMemsetAsync(bucket_cursor, 0, 256 * 4, stream);
    k_prep_w<<<256, 128, 0, stream>>>(Wl1, Wr1, bl1, br1, Wl2, Wr2, bl2, br2, Wo, bo,
                                      W1, W2, Wob, bias1, bias2, biaso, wcard1);

    const int PBLK = (N_EDGES + PT - 1) / PT;   // 391
    k_partition<<<PBLK, 256, 0, stream>>>(e_src, e_dst, bucket_cursor, part);
    k_bucket<<<NB, 256, 0, stream>>>(part, bucket_cursor,
                                     row_off, deg_i, dinv, csr_src);

    // layer 1 (reads f32 x directly, converts in-register)
    k_gemm_dual<<<GEMM_BLOCKS, 256, 0, stream>>>(nullptr, x, cards, W1, bias1, wcard1, Gq, Rb, 1);
    k_agg<<<N_NODES / 4, 256, 0, stream>>>(Gq, Rb, row_off, deg_i, dinv, csr_src, bufH);
    // layer 2
    k_gemm_dual<<<GEMM_BLOCKS, 256, 0, stream>>>(bufH, nullptr, nullptr, W2, bias2, wcard1, Gq, Rb, 0);
    k_agg<<<N_NODES / 4, 256, 0, stream>>>(Gq, Rb, row_off, deg_i, dinv, csr_src, bufH);
    // output
    k_gemm_logits<<<GEMM_BLOCKS, 256, 0, stream>>>(bufH, Wob, biaso, logits);
}